// Round 11
// baseline (267.052 us; speedup 1.0000x reference)
//
#include <hip/hip_runtime.h>
#include <hip/hip_bf16.h>
#include <math.h>

#define NN 512
#define CSD 384
#define CZ 128
#define HH 12
#define TMPW 1152          // 192 sq | 192 sk | 192 sv | 144 pq | 144 pk | 288 pv
#define CATH 176
#define CATDIM 2112
#define NSPLIT 6
#define KSPL 352

#define SW 0.14433756729740643f
#define PW 0.13608276348795434f
#define ZW 0.57735026918962576f
#define NEG_INF -3.4028234663852886e38f

typedef float f32x4_t __attribute__((ext_vector_type(4)));
typedef short bf16x8_t __attribute__((ext_vector_type(8)));

union BFU { uint4 q; bf16x8_t v; ushort u[8]; };

static __device__ __forceinline__ ushort f2bf(float f) {
    __hip_bfloat16 h = __float2bfloat16(f);
    return *reinterpret_cast<ushort*>(&h);
}
static __device__ __forceinline__ float bf2f(ushort u) {
    unsigned int v = ((unsigned int)u) << 16;
    return __uint_as_float(v);
}

// ---------------- proj GEMM + fused rotation: tmp[512][1152] = s @ Wcat + bias
__global__ void proj_gemm_kernel(const float* __restrict__ s, const float* __restrict__ rot,
                                 const float* __restrict__ tran,
                                 const float* __restrict__ Wsq, const float* __restrict__ bsq,
                                 const float* __restrict__ Wsk, const float* __restrict__ bsk,
                                 const float* __restrict__ Wsv, const float* __restrict__ bsv,
                                 const float* __restrict__ Wpq, const float* __restrict__ bpq,
                                 const float* __restrict__ Wpk, const float* __restrict__ bpk,
                                 const float* __restrict__ Wpv, const float* __restrict__ bpv,
                                 float* __restrict__ tmp)
{
    int bx = blockIdx.x;            // 24 f-tiles of 48
    int n0 = blockIdx.y * 32;       // 16 n-tiles
    int f0 = bx * 48;
    const float* W; const float* bb; int dout; int segstart;
    if (bx < 4)       { W = Wsq; bb = bsq; dout = 192; segstart = 0; }
    else if (bx < 8)  { W = Wsk; bb = bsk; dout = 192; segstart = 192; }
    else if (bx < 12) { W = Wsv; bb = bsv; dout = 192; segstart = 384; }
    else if (bx < 15) { W = Wpq; bb = bpq; dout = 144; segstart = 576; }
    else if (bx < 18) { W = Wpk; bb = bpk; dout = 144; segstart = 720; }
    else              { W = Wpv; bb = bpv; dout = 288; segstart = 864; }
    int colbase = f0 - segstart;

    __shared__ float St[32][34];
    __shared__ float Ws[32][49];
    int tid = threadIdx.x;
    int ty = tid >> 4, tx = tid & 15;
    float acc[2][3] = {{0,0,0},{0,0,0}};

    for (int k0 = 0; k0 < CSD; k0 += 32) {
        {
            int r = tid >> 3, c4 = (tid & 7) * 4;
            float4 v = *(const float4*)&s[(size_t)(n0 + r) * CSD + k0 + c4];
            St[c4 + 0][r] = v.x; St[c4 + 1][r] = v.y; St[c4 + 2][r] = v.z; St[c4 + 3][r] = v.w;
        }
        for (int e = tid; e < 1536; e += 256) {
            int r = e / 48, c = e % 48;
            Ws[r][c] = W[(size_t)(k0 + r) * dout + colbase + c];
        }
        __syncthreads();
        #pragma unroll
        for (int k = 0; k < 32; k++) {
            float2 a = *(const float2*)&St[k][ty * 2];
            float b0 = Ws[k][tx * 3], b1 = Ws[k][tx * 3 + 1], b2 = Ws[k][tx * 3 + 2];
            acc[0][0] += a.x * b0; acc[0][1] += a.x * b1; acc[0][2] += a.x * b2;
            acc[1][0] += a.y * b0; acc[1][1] += a.y * b1; acc[1][2] += a.y * b2;
        }
        __syncthreads();
    }
    float bv0 = bb[colbase + tx * 3], bv1 = bb[colbase + tx * 3 + 1], bv2 = bb[colbase + tx * 3 + 2];
    #pragma unroll
    for (int r = 0; r < 2; r++) {
        int n = n0 + ty * 2 + r;
        float v0 = acc[r][0] + bv0, v1 = acc[r][1] + bv1, v2 = acc[r][2] + bv2;
        float* o = tmp + (size_t)n * TMPW + f0 + tx * 3;
        if (bx >= 12) {
            const float* R = rot + n * 9;
            const float* T = tran + n * 3;
            float g0 = R[0] * v0 + R[1] * v1 + R[2] * v2 + T[0];
            float g1 = R[3] * v0 + R[4] * v1 + R[5] * v2 + T[1];
            float g2 = R[6] * v0 + R[7] * v1 + R[8] * v2 + T[2];
            o[0] = g0; o[1] = g1; o[2] = g2;
        } else {
            o[0] = v0; o[1] = v1; o[2] = v2;
        }
    }
}

// ---------------- K1: sbz-in-registers + logits + softmax. Block per i, 256 thr.
// Per-tile loop (8 tiles/wave, zero barriers): prefetch z -> MFMA (acc = pair bias,
// col=h row=j) -> same lane computes logits for its (h = l16, 4 j's) -> lt.
// Then one barrier + softmax -> attn_bf (bf16).
__global__ __launch_bounds__(256, 4) void sbz_logits_softmax_kernel(
        const float* __restrict__ z, const float* __restrict__ resm,
        const float* __restrict__ Wsb, const float* __restrict__ bsb,
        const float* __restrict__ watt, const float* __restrict__ batt,
        const float* __restrict__ tpw, const float* __restrict__ tmp,
        ushort* __restrict__ attn_bf)
{
    int i = blockIdx.x;
    __shared__ float lt[NN * 17];       // 34.8 KB logits [j][h]
    __shared__ float sqs[12 * 24];      // scaled sq, stride 24 (16B-aligned float4)
    __shared__ float pqi[12 * 24];      // pq, stride 24
    __shared__ float cpt[12];
    __shared__ float cb[12];
    int tid = threadIdx.x;
    int w = tid >> 6, lane = tid & 63;
    int l16 = lane & 15, lhi = lane >> 4;
    float w0 = watt[0], w1 = watt[1], w2 = watt[2], ba = batt[0];
    float A2 = w2 * ZW;

    if (tid < 192) {
        int h = tid >> 4, d = tid & 15;
        sqs[h * 24 + d] = tmp[(size_t)i * TMPW + tid] * (SW * w0);
    }
    if (tid < 144) {
        int h = tid / 12, d = tid % 12;
        pqi[h * 24 + d] = tmp[(size_t)i * TMPW + 576 + tid];
    }
    if (tid < 12) {
        cpt[tid] = -0.5f * log1pf(expf(tpw[tid])) * PW * w1;
        cb[tid]  = A2 * bsb[tid] + ba;
    }

    // Wsb B-fragments in registers
    BFU breg[4];
    #pragma unroll
    for (int kk = 0; kk < 4; kk++) {
        #pragma unroll
        for (int e = 0; e < 8; e++) {
            int k = kk * 32 + lhi * 8 + e;
            float v = (l16 < HH) ? Wsb[k * HH + l16] * A2 : 0.f;
            breg[kk].u[e] = f2bf(v);
        }
    }
    __syncthreads();

    const float* zi = z + (size_t)i * NN * CZ;
    float rmi = resm[i];
    float cpth = cpt[l16 < HH ? l16 : 0];
    float cbh  = cb[l16 < HH ? l16 : 0];

    float4 prA[8], prB[8];
    {   // prefetch tile 0 (rows w*16 + l16)
        const float* zr = zi + (size_t)(w * 16 + l16) * CZ + lhi * 8;
        #pragma unroll
        for (int kk = 0; kk < 4; kk++) {
            prA[kk * 2]     = *(const float4*)&zr[kk * 32];
            prA[kk * 2 + 1] = *(const float4*)&zr[kk * 32 + 4];
        }
    }

    for (int t = 0; t < 8; t++) {
        float4* cur = (t & 1) ? prB : prA;
        float4* nxt = (t & 1) ? prA : prB;
        if (t < 7) {    // prefetch next tile: rows (w + 4(t+1))*16 + l16
            const float* zr = zi + (size_t)((w + 4 * (t + 1)) * 16 + l16) * CZ + lhi * 8;
            #pragma unroll
            for (int kk = 0; kk < 4; kk++) {
                nxt[kk * 2]     = *(const float4*)&zr[kk * 32];
                nxt[kk * 2 + 1] = *(const float4*)&zr[kk * 32 + 4];
            }
        }
        // MFMA: pair-bias for this tile's 16 rows
        f32x4_t acc = {0.f, 0.f, 0.f, 0.f};
        #pragma unroll
        for (int kk = 0; kk < 4; kk++) {
            float4 f0 = cur[kk * 2], f1 = cur[kk * 2 + 1];
            BFU a;
            a.u[0] = f2bf(f0.x); a.u[1] = f2bf(f0.y); a.u[2] = f2bf(f0.z); a.u[3] = f2bf(f0.w);
            a.u[4] = f2bf(f1.x); a.u[5] = f2bf(f1.y); a.u[6] = f2bf(f1.z); a.u[7] = f2bf(f1.w);
            acc = __builtin_amdgcn_mfma_f32_16x16x32_bf16(a.v, breg[kk].v, acc, 0, 0, 0);
        }
        // logits for this tile: lane handles h = l16 (<12), j = jbase + lhi*4 + r
        if (l16 < HH) {
            int h = l16;
            int jbase = (w + 4 * t) * 16;
            const float4* sqp = (const float4*)&sqs[h * 24];
            const float4* pqp = (const float4*)&pqi[h * 24];
            #pragma unroll
            for (int r = 0; r < 4; r++) {
                int j = jbase + lhi * 4 + r;
                float mj = rmi * resm[j];
                const float4* skp = (const float4*)(tmp + (size_t)j * TMPW + 192 + h * 16);
                float d0 = 0.f;
                #pragma unroll
                for (int q = 0; q < 4; q++) {
                    float4 kv = skp[q];
                    float4 qv = sqp[q];
                    d0 += qv.x * kv.x + qv.y * kv.y + qv.z * kv.z + qv.w * kv.w;
                }
                const float4* pkp = (const float4*)(tmp + (size_t)j * TMPW + 720 + h * 12);
                float sd = 0.f;
                #pragma unroll
                for (int q = 0; q < 3; q++) {
                    float4 kv = pkp[q];
                    float4 qv = pqp[q];
                    float a = qv.x - kv.x, bb2 = qv.y - kv.y, cc = qv.z - kv.z, e = qv.w - kv.w;
                    sd += a * a + bb2 * bb2 + cc * cc + e * e;
                }
                float lg = cbh + acc[r] + d0 + cpth * sd;
                if (mj == 0.f) lg = NEG_INF;
                lt[j * 17 + h] = lg;
            }
        }
    }
    __syncthreads();

    // softmax: wave w -> heads 3w..3w+2; write bf16 attn
    #pragma unroll
    for (int t = 0; t < 3; t++) {
        int h = w * 3 + t;
        float v[8]; float m = -INFINITY;
        #pragma unroll
        for (int u = 0; u < 8; u++) { v[u] = lt[(lane + 64 * u) * 17 + h]; m = fmaxf(m, v[u]); }
        for (int off = 32; off; off >>= 1) m = fmaxf(m, __shfl_xor(m, off));
        float ssum = 0.f;
        #pragma unroll
        for (int u = 0; u < 8; u++) { v[u] = __expf(v[u] - m); ssum += v[u]; }
        for (int off = 32; off; off >>= 1) ssum += __shfl_xor(ssum, off);
        float inv = 1.f / ssum;
        ushort* ag = attn_bf + ((size_t)i * HH + h) * NN;
        #pragma unroll
        for (int u = 0; u < 8; u++) ag[lane + 64 * u] = f2bf(v[u] * inv);
    }
}

// ---------------- K2: r_pair f32 streaming. Block per i, 256 thr (4 blocks/CU).
// wave = j-quarter; lane = 2 channels (float2, 512B/issue); 16-deep unroll.
// P staged bf16 [j][12] rows, read as 3 uint2 broadcast.
__global__ __launch_bounds__(256, 4) void rpair_kernel(const float* __restrict__ z,
                                                       const ushort* __restrict__ attn_bf,
                                                       float* __restrict__ cat)
{
    int i = blockIdx.x;
    __shared__ ushort pbf[NN * 12];         // 12.3 KB  P[j][h] bf16
    __shared__ float pslab[4 * 12 * 128];   // 24.6 KB
    int tid = threadIdx.x;

    for (int e = tid; e < 768; e += 256) {  // 12 heads x 64 granules of 8
        int h = e >> 6, g = e & 63;
        BFU v; v.q = *(const uint4*)&attn_bf[((size_t)i * HH + h) * NN + g * 8];
        #pragma unroll
        for (int q = 0; q < 8; q++) pbf[(g * 8 + q) * 12 + h] = v.u[q];
    }
    __syncthreads();

    int w = tid >> 6, lane = tid & 63;
    int c0 = lane * 2;
    const float* zq = z + ((size_t)i * NN + w * 128) * CZ + c0;
    float acc[12][2];
    #pragma unroll
    for (int h = 0; h < 12; h++) { acc[h][0] = 0.f; acc[h][1] = 0.f; }

    for (int j0 = 0; j0 < 128; j0 += 16) {
        float2 zv[16];
        #pragma unroll
        for (int u = 0; u < 16; u++) zv[u] = *(const float2*)&zq[(size_t)(j0 + u) * CZ];
        #pragma unroll
        for (int u = 0; u < 16; u++) {
            int j = w * 128 + j0 + u;
            const uint2* pr = (const uint2*)&pbf[j * 12];
            uint2 pa = pr[0], pb2 = pr[1], pc = pr[2];
            float ph[12];
            ph[0]  = bf2f((ushort)(pa.x & 0xffff)); ph[1]  = bf2f((ushort)(pa.x >> 16));
            ph[2]  = bf2f((ushort)(pa.y & 0xffff)); ph[3]  = bf2f((ushort)(pa.y >> 16));
            ph[4]  = bf2f((ushort)(pb2.x & 0xffff)); ph[5]  = bf2f((ushort)(pb2.x >> 16));
            ph[6]  = bf2f((ushort)(pb2.y & 0xffff)); ph[7]  = bf2f((ushort)(pb2.y >> 16));
            ph[8]  = bf2f((ushort)(pc.x & 0xffff)); ph[9]  = bf2f((ushort)(pc.x >> 16));
            ph[10] = bf2f((ushort)(pc.y & 0xffff)); ph[11] = bf2f((ushort)(pc.y >> 16));
            #pragma unroll
            for (int h = 0; h < 12; h++) {
                acc[h][0] += ph[h] * zv[u].x;
                acc[h][1] += ph[h] * zv[u].y;
            }
        }
    }
    #pragma unroll
    for (int h = 0; h < 12; h++)
        *(float2*)&pslab[(w * 12 + h) * 128 + c0] = make_float2(acc[h][0], acc[h][1]);
    __syncthreads();

    for (int e = tid; e < 1536; e += 256) {
        int h = e >> 7, c = e & 127;
        float ssum = pslab[h * 128 + c] + pslab[(12 + h) * 128 + c]
                   + pslab[(24 + h) * 128 + c] + pslab[(36 + h) * 128 + c];
        cat[(size_t)i * CATDIM + h * CATH + 48 + c] = ssum;
    }
}

// ---------------- per-head r_scalar + r_pt (+rotate back, norm); attn bf16
__global__ void head_sum_kernel(const ushort* __restrict__ attn_bf, const float* __restrict__ tmp,
                                const float* __restrict__ rot, const float* __restrict__ tran,
                                float* __restrict__ cat)
{
    int i0 = blockIdx.x * 32;
    int h  = blockIdx.y;
    __shared__ float At[32][65];
    __shared__ float Sr[64][44];
    __shared__ float Rp[32][24];
    int tid = threadIdx.x;
    int il = tid & 31, fg = tid >> 5;
    float acc[5] = {0,0,0,0,0};

    for (int jc = 0; jc < NN; jc += 64) {
        {
            int r = tid >> 3, c8 = (tid & 7) * 8;
            const ushort* src = attn_bf + ((size_t)(i0 + r) * HH + h) * NN + jc + c8;
            BFU v; v.q = *(const uint4*)src;
            #pragma unroll
            for (int q = 0; q < 8; q++) At[r][c8 + q] = bf2f(v.u[q]);
        }
        {
            int jr = tid >> 2, d4 = (tid & 3) * 4;
            *(float4*)&Sr[jr][d4] = *(const float4*)&tmp[(size_t)(jc + jr) * TMPW + 384 + h * 16 + d4];
        }
        for (int e = tid; e < 384; e += 256) {
            int jr = e / 6, p4 = (e % 6) * 4;
            *(float4*)&Sr[jr][16 + p4] = *(const float4*)&tmp[(size_t)(jc + jr) * TMPW + 864 + h * 24 + p4];
        }
        __syncthreads();
        #pragma unroll 4
        for (int j = 0; j < 64; j++) {
            float a = At[il][j];
            #pragma unroll
            for (int q = 0; q < 5; q++) acc[q] += a * Sr[j][fg * 5 + q];
        }
        __syncthreads();
    }

    float* cbase = cat + (size_t)(i0 + il) * CATDIM + h * CATH;
    #pragma unroll
    for (int q = 0; q < 5; q++) {
        int f = fg * 5 + q;
        if (f < 16) cbase[f] = acc[q];
        else Rp[il][f - 16] = acc[q];
    }
    __syncthreads();

    {
        int il2 = tid >> 3, p = tid & 7;
        int i = i0 + il2;
        float gx = Rp[il2][p * 3 + 0] - tran[i * 3 + 0];
        float gy = Rp[il2][p * 3 + 1] - tran[i * 3 + 1];
        float gz = Rp[il2][p * 3 + 2] - tran[i * 3 + 2];
        const float* R = rot + i * 9;
        float lx = R[0] * gx + R[3] * gy + R[6] * gz;
        float ly = R[1] * gx + R[4] * gy + R[7] * gz;
        float lz = R[2] * gx + R[5] * gy + R[8] * gz;
        float nrm = sqrtf(lx * lx + ly * ly + lz * lz + 1e-8f);
        float* cp = cat + (size_t)i * CATDIM + h * CATH;
        cp[16 + p * 3 + 0] = lx; cp[16 + p * 3 + 1] = ly; cp[16 + p * 3 + 2] = lz;
        cp[40 + p] = nrm;
    }
}

// ---------------- out GEMM, K-split
__global__ void out_gemm_split_kernel(const float* __restrict__ cat, const float* __restrict__ Wout,
                                      float* __restrict__ part)
{
    int n0 = blockIdx.x * 64;
    int i0 = blockIdx.y * 64;
    int ks = blockIdx.z * KSPL;
    __shared__ float St[32][68];
    __shared__ float Bs[32][68];
    int tid = threadIdx.x;
    int ty = tid >> 4, tx = tid & 15;
    float acc[4][4] = {{0,0,0,0},{0,0,0,0},{0,0,0,0},{0,0,0,0}};

    for (int k0 = 0; k0 < KSPL; k0 += 32) {
        {
            int r = tid >> 2, c8 = (tid & 3) * 8;
            const float* src = cat + (size_t)(i0 + r) * CATDIM + ks + k0 + c8;
            float4 v0 = *(const float4*)src;
            float4 v1 = *(const float4*)(src + 4);
            St[c8+0][r]=v0.x; St[c8+1][r]=v0.y; St[c8+2][r]=v0.z; St[c8+3][r]=v0.w;
            St[c8+4][r]=v1.x; St[c8+5][r]=v1.y; St[c8+6][r]=v1.z; St[c8+7][r]=v1.w;
        }
        {
            int r = tid >> 3, c8 = (tid & 7) * 8;
            const float* src = Wout + (size_t)(ks + k0 + r) * CSD + n0 + c8;
            *(float4*)&Bs[r][c8]     = *(const float4*)src;
            *(float4*)&Bs[r][c8 + 4] = *(const float4*)(src + 4);
        }
        __syncthreads();
        #pragma unroll
        for (int k = 0; k < 32; k++) {
            float4 a = *(const float4*)&St[k][ty * 4];
            float4 b = *(const float4*)&Bs[k][tx * 4];
            float av[4] = {a.x, a.y, a.z, a.w};
            float bv[4] = {b.x, b.y, b.z, b.w};
            #pragma unroll
            for (int r = 0; r < 4; r++)
                #pragma unroll
                for (int c = 0; c < 4; c++) acc[r][c] += av[r] * bv[c];
        }
        __syncthreads();
    }
    #pragma unroll
    for (int r = 0; r < 4; r++) {
        float4 v = make_float4(acc[r][0], acc[r][1], acc[r][2], acc[r][3]);
        *(float4*)&part[((size_t)blockIdx.z * NN + i0 + ty * 4 + r) * CSD + n0 + tx * 4] = v;
    }
}

__global__ void reduce_out_kernel(const float* __restrict__ part, const float* __restrict__ bout,
                                  float* __restrict__ out)
{
    int v = blockIdx.x * 256 + threadIdx.x;
    int n4 = v % 96;
    float4 o = ((const float4*)bout)[n4];
    const float4* p4 = (const float4*)part;
    #pragma unroll
    for (int s = 0; s < NSPLIT; s++) {
        float4 t = p4[(size_t)s * 49152 + v];
        o.x += t.x; o.y += t.y; o.z += t.z; o.w += t.w;
    }
    ((float4*)out)[v] = o;
}

extern "C" void kernel_launch(void* const* d_in, const int* in_sizes, int n_in,
                              void* d_out, int out_size, void* d_ws, size_t ws_size,
                              hipStream_t stream) {
    const float* s    = (const float*)d_in[0];
    const float* z    = (const float*)d_in[1];
    const float* rot  = (const float*)d_in[2];
    const float* tran = (const float*)d_in[3];
    const float* resm = (const float*)d_in[4];
    const float* Wsq  = (const float*)d_in[5];  const float* bsq = (const float*)d_in[6];
    const float* Wsk  = (const float*)d_in[7];  const float* bsk = (const float*)d_in[8];
    const float* Wsv  = (const float*)d_in[9];  const float* bsv = (const float*)d_in[10];
    const float* Wsb  = (const float*)d_in[11]; const float* bsb = (const float*)d_in[12];
    const float* Wpq  = (const float*)d_in[13]; const float* bpq = (const float*)d_in[14];
    const float* Wpk  = (const float*)d_in[15]; const float* bpk = (const float*)d_in[16];
    const float* Wpv  = (const float*)d_in[17]; const float* bpv = (const float*)d_in[18];
    const float* watt = (const float*)d_in[19]; const float* batt = (const float*)d_in[20];
    const float* tpw  = (const float*)d_in[21];
    const float* Wout = (const float*)d_in[22]; const float* bout = (const float*)d_in[23];
    float* out = (float*)d_out;
    float* ws  = (float*)d_ws;

    float*  tmp     = ws;                        // 589824 floats
    ushort* attn_bf = (ushort*)(ws + 589824);    // 3145728 ushorts (1572864 f-slots)
    float*  cat     = ws + 589824 + 1572864;     // 1081344 floats
    float*  partO   = cat + 1081344;             // 1179648 floats

    proj_gemm_kernel<<<dim3(24, 16), 256, 0, stream>>>(s, rot, tran,
                                                       Wsq, bsq, Wsk, bsk, Wsv, bsv,
                                                       Wpq, bpq, Wpk, bpk, Wpv, bpv, tmp);
    sbz_logits_softmax_kernel<<<512, 256, 0, stream>>>(z, resm, Wsb, bsb, watt, batt,
                                                       tpw, tmp, attn_bf);
    rpair_kernel<<<512, 256, 0, stream>>>(z, attn_bf, cat);
    head_sum_kernel<<<dim3(16, 12), 256, 0, stream>>>(attn_bf, tmp, rot, tran, cat);
    out_gemm_split_kernel<<<dim3(6, 8, NSPLIT), 256, 0, stream>>>(cat, Wout, partO);
    reduce_out_kernel<<<192, 256, 0, stream>>>(partO, bout, out);
}

// Round 12
// 200.453 us; speedup vs baseline: 1.3322x; 1.3322x over previous
//
#include <hip/hip_runtime.h>
#include <hip/hip_bf16.h>
#include <math.h>

#define NN 512
#define CSD 384
#define CZ 128
#define HH 12
#define TMPW 1152          // 192 sq | 192 sk | 192 sv | 144 pq | 144 pk | 288 pv
#define CATH 176
#define CATDIM 2112
#define NSPLIT 6
#define KSPL 352

#define SW 0.14433756729740643f
#define PW 0.13608276348795434f
#define ZW 0.57735026918962576f
#define NEG_INF -3.4028234663852886e38f

typedef float f32x4_t __attribute__((ext_vector_type(4)));
typedef short bf16x8_t __attribute__((ext_vector_type(8)));

union BFU { uint4 q; bf16x8_t v; ushort u[8]; };

static __device__ __forceinline__ ushort f2bf(float f) {
    __hip_bfloat16 h = __float2bfloat16(f);
    return *reinterpret_cast<ushort*>(&h);
}
static __device__ __forceinline__ float bf2f(ushort u) {
    unsigned int v = ((unsigned int)u) << 16;
    return __uint_as_float(v);
}

// ---------------- proj GEMM + fused rotation: tmp[512][1152] = s @ Wcat + bias
__global__ void proj_gemm_kernel(const float* __restrict__ s, const float* __restrict__ rot,
                                 const float* __restrict__ tran,
                                 const float* __restrict__ Wsq, const float* __restrict__ bsq,
                                 const float* __restrict__ Wsk, const float* __restrict__ bsk,
                                 const float* __restrict__ Wsv, const float* __restrict__ bsv,
                                 const float* __restrict__ Wpq, const float* __restrict__ bpq,
                                 const float* __restrict__ Wpk, const float* __restrict__ bpk,
                                 const float* __restrict__ Wpv, const float* __restrict__ bpv,
                                 float* __restrict__ tmp)
{
    int bx = blockIdx.x;            // 24 f-tiles of 48
    int n0 = blockIdx.y * 32;       // 16 n-tiles
    int f0 = bx * 48;
    const float* W; const float* bb; int dout; int segstart;
    if (bx < 4)       { W = Wsq; bb = bsq; dout = 192; segstart = 0; }
    else if (bx < 8)  { W = Wsk; bb = bsk; dout = 192; segstart = 192; }
    else if (bx < 12) { W = Wsv; bb = bsv; dout = 192; segstart = 384; }
    else if (bx < 15) { W = Wpq; bb = bpq; dout = 144; segstart = 576; }
    else if (bx < 18) { W = Wpk; bb = bpk; dout = 144; segstart = 720; }
    else              { W = Wpv; bb = bpv; dout = 288; segstart = 864; }
    int colbase = f0 - segstart;

    __shared__ float St[32][34];
    __shared__ float Ws[32][49];
    int tid = threadIdx.x;
    int ty = tid >> 4, tx = tid & 15;
    float acc[2][3] = {{0,0,0},{0,0,0}};

    for (int k0 = 0; k0 < CSD; k0 += 32) {
        {
            int r = tid >> 3, c4 = (tid & 7) * 4;
            float4 v = *(const float4*)&s[(size_t)(n0 + r) * CSD + k0 + c4];
            St[c4 + 0][r] = v.x; St[c4 + 1][r] = v.y; St[c4 + 2][r] = v.z; St[c4 + 3][r] = v.w;
        }
        for (int e = tid; e < 1536; e += 256) {
            int r = e / 48, c = e % 48;
            Ws[r][c] = W[(size_t)(k0 + r) * dout + colbase + c];
        }
        __syncthreads();
        #pragma unroll
        for (int k = 0; k < 32; k++) {
            float2 a = *(const float2*)&St[k][ty * 2];
            float b0 = Ws[k][tx * 3], b1 = Ws[k][tx * 3 + 1], b2 = Ws[k][tx * 3 + 2];
            acc[0][0] += a.x * b0; acc[0][1] += a.x * b1; acc[0][2] += a.x * b2;
            acc[1][0] += a.y * b0; acc[1][1] += a.y * b1; acc[1][2] += a.y * b2;
        }
        __syncthreads();
    }
    float bv0 = bb[colbase + tx * 3], bv1 = bb[colbase + tx * 3 + 1], bv2 = bb[colbase + tx * 3 + 2];
    #pragma unroll
    for (int r = 0; r < 2; r++) {
        int n = n0 + ty * 2 + r;
        float v0 = acc[r][0] + bv0, v1 = acc[r][1] + bv1, v2 = acc[r][2] + bv2;
        float* o = tmp + (size_t)n * TMPW + f0 + tx * 3;
        if (bx >= 12) {
            const float* R = rot + n * 9;
            const float* T = tran + n * 3;
            float g0 = R[0] * v0 + R[1] * v1 + R[2] * v2 + T[0];
            float g1 = R[3] * v0 + R[4] * v1 + R[5] * v2 + T[1];
            float g2 = R[6] * v0 + R[7] * v1 + R[8] * v2 + T[2];
            o[0] = g0; o[1] = g1; o[2] = g2;
        } else {
            o[0] = v0; o[1] = v1; o[2] = v2;
        }
    }
}

// ---------------- L1: logits with register-MFMA pair bias.
// grid (4 j-chunks, 512 i), block 256. Wave w -> 2 tiles of 16 j. No big LDS.
// Writes logits f32 [i][h][j].
__global__ __launch_bounds__(256) void logits_kernel(
        const float* __restrict__ z, const float* __restrict__ resm,
        const float* __restrict__ Wsb, const float* __restrict__ bsb,
        const float* __restrict__ watt, const float* __restrict__ batt,
        const float* __restrict__ tpw, const float* __restrict__ tmp,
        float* __restrict__ lgts)
{
    int jc = blockIdx.x;            // 0..3 (128 j each)
    int i  = blockIdx.y;
    __shared__ float sqs[12 * 24];
    __shared__ float pqi[12 * 24];
    __shared__ float cpt[12];
    __shared__ float cb[12];
    int tid = threadIdx.x;
    int w = tid >> 6, lane = tid & 63;
    int l16 = lane & 15, lhi = lane >> 4;
    float w0 = watt[0], w1 = watt[1], w2 = watt[2], ba = batt[0];
    float A2 = w2 * ZW;

    if (tid < 192) {
        int h = tid >> 4, d = tid & 15;
        sqs[h * 24 + d] = tmp[(size_t)i * TMPW + tid] * (SW * w0);
    }
    if (tid < 144) {
        int h = tid / 12, d = tid % 12;
        pqi[h * 24 + d] = tmp[(size_t)i * TMPW + 576 + tid];
    }
    if (tid < 12) {
        cpt[tid] = -0.5f * log1pf(expf(tpw[tid])) * PW * w1;
        cb[tid]  = A2 * bsb[tid] + ba;
    }

    BFU breg[4];
    #pragma unroll
    for (int kk = 0; kk < 4; kk++) {
        #pragma unroll
        for (int e = 0; e < 8; e++) {
            int k = kk * 32 + lhi * 8 + e;
            float v = (l16 < HH) ? Wsb[k * HH + l16] * A2 : 0.f;
            breg[kk].u[e] = f2bf(v);
        }
    }
    __syncthreads();

    const float* zi = z + (size_t)i * NN * CZ;
    float rmi = resm[i];
    float cpth = cpt[l16 < HH ? l16 : 0];
    float cbh  = cb[l16 < HH ? l16 : 0];

    #pragma unroll
    for (int t = 0; t < 2; t++) {
        int jbase = jc * 128 + (w * 2 + t) * 16;
        // load this tile's z rows (row = jbase + l16)
        const float* zr = zi + (size_t)(jbase + l16) * CZ + lhi * 8;
        float4 pr[8];
        #pragma unroll
        for (int kk = 0; kk < 4; kk++) {
            pr[kk * 2]     = *(const float4*)&zr[kk * 32];
            pr[kk * 2 + 1] = *(const float4*)&zr[kk * 32 + 4];
        }
        f32x4_t acc = {0.f, 0.f, 0.f, 0.f};
        #pragma unroll
        for (int kk = 0; kk < 4; kk++) {
            float4 f0 = pr[kk * 2], f1 = pr[kk * 2 + 1];
            BFU a;
            a.u[0] = f2bf(f0.x); a.u[1] = f2bf(f0.y); a.u[2] = f2bf(f0.z); a.u[3] = f2bf(f0.w);
            a.u[4] = f2bf(f1.x); a.u[5] = f2bf(f1.y); a.u[6] = f2bf(f1.z); a.u[7] = f2bf(f1.w);
            acc = __builtin_amdgcn_mfma_f32_16x16x32_bf16(a.v, breg[kk].v, acc, 0, 0, 0);
        }
        if (l16 < HH) {
            int h = l16;
            const float4* sqp = (const float4*)&sqs[h * 24];
            const float4* pqp = (const float4*)&pqi[h * 24];
            #pragma unroll
            for (int r = 0; r < 4; r++) {
                int j = jbase + lhi * 4 + r;
                float mj = rmi * resm[j];
                const float4* skp = (const float4*)(tmp + (size_t)j * TMPW + 192 + h * 16);
                float d0 = 0.f;
                #pragma unroll
                for (int q = 0; q < 4; q++) {
                    float4 kv = skp[q];
                    float4 qv = sqp[q];
                    d0 += qv.x * kv.x + qv.y * kv.y + qv.z * kv.z + qv.w * kv.w;
                }
                const float4* pkp = (const float4*)(tmp + (size_t)j * TMPW + 720 + h * 12);
                float sd = 0.f;
                #pragma unroll
                for (int q = 0; q < 3; q++) {
                    float4 kv = pkp[q];
                    float4 qv = pqp[q];
                    float a = qv.x - kv.x, bb2 = qv.y - kv.y, cc = qv.z - kv.z, e = qv.w - kv.w;
                    sd += a * a + bb2 * bb2 + cc * cc + e * e;
                }
                float lg = cbh + acc[r] + d0 + cpth * sd;
                if (mj == 0.f) lg = NEG_INF;
                lgts[((size_t)i * HH + h) * NN + j] = lg;
            }
        }
    }
}

// ---------------- L2: softmax. One wave per (i,h) row; 1536 blocks x 4 waves.
__global__ __launch_bounds__(256) void softmax_kernel(const float* __restrict__ lgts,
                                                      ushort* __restrict__ attn_bf)
{
    int tid = threadIdx.x;
    int w = tid >> 6, lane = tid & 63;
    int gid = blockIdx.x * 4 + w;           // (i,h) pair: 6144 total
    const float* row = lgts + (size_t)gid * NN;
    float v[8]; float m = -INFINITY;
    #pragma unroll
    for (int u = 0; u < 8; u++) { v[u] = row[lane + 64 * u]; m = fmaxf(m, v[u]); }
    for (int off = 32; off; off >>= 1) m = fmaxf(m, __shfl_xor(m, off));
    float ssum = 0.f;
    #pragma unroll
    for (int u = 0; u < 8; u++) { v[u] = __expf(v[u] - m); ssum += v[u]; }
    for (int off = 32; off; off >>= 1) ssum += __shfl_xor(ssum, off);
    float inv = 1.f / ssum;
    ushort* ag = attn_bf + (size_t)gid * NN;
    #pragma unroll
    for (int u = 0; u < 8; u++) ag[lane + 64 * u] = f2bf(v[u] * inv);
}

// ---------------- rpair partials: grid (4 jq, 512 i), block 256.
// wave w -> 32 j; lane -> channels (2*lane, 2*lane+1). f32 exact.
__global__ __launch_bounds__(256) void rpair_kernel(const float* __restrict__ z,
                                                    const ushort* __restrict__ attn_bf,
                                                    float* __restrict__ part)
{
    int jq = blockIdx.x;
    int i  = blockIdx.y;
    __shared__ ushort pbf[128 * 12];        // 3 KB  P[j][h] bf16 for this j-quarter
    __shared__ float pslab[4 * 12 * 128];   // 24.6 KB
    int tid = threadIdx.x;

    if (tid < 192) {                        // 12 h x 16 granules of 8 j
        int h = tid >> 4, g = tid & 15;
        BFU v; v.q = *(const uint4*)&attn_bf[((size_t)i * HH + h) * NN + jq * 128 + g * 8];
        #pragma unroll
        for (int q = 0; q < 8; q++) pbf[(g * 8 + q) * 12 + h] = v.u[q];
    }
    __syncthreads();

    int w = tid >> 6, lane = tid & 63;
    int c0 = lane * 2;
    const float* zq = z + ((size_t)i * NN + jq * 128 + w * 32) * CZ + c0;
    float acc[12][2];
    #pragma unroll
    for (int h = 0; h < 12; h++) { acc[h][0] = 0.f; acc[h][1] = 0.f; }

    for (int j0 = 0; j0 < 32; j0 += 8) {
        float2 zv[8];
        #pragma unroll
        for (int u = 0; u < 8; u++) zv[u] = *(const float2*)&zq[(size_t)(j0 + u) * CZ];
        #pragma unroll
        for (int u = 0; u < 8; u++) {
            int jl = w * 32 + j0 + u;
            const uint2* pr = (const uint2*)&pbf[jl * 12];
            uint2 pa = pr[0], pb2 = pr[1], pc = pr[2];
            float ph[12];
            ph[0]  = bf2f((ushort)(pa.x & 0xffff)); ph[1]  = bf2f((ushort)(pa.x >> 16));
            ph[2]  = bf2f((ushort)(pa.y & 0xffff)); ph[3]  = bf2f((ushort)(pa.y >> 16));
            ph[4]  = bf2f((ushort)(pb2.x & 0xffff)); ph[5]  = bf2f((ushort)(pb2.x >> 16));
            ph[6]  = bf2f((ushort)(pb2.y & 0xffff)); ph[7]  = bf2f((ushort)(pb2.y >> 16));
            ph[8]  = bf2f((ushort)(pc.x & 0xffff)); ph[9]  = bf2f((ushort)(pc.x >> 16));
            ph[10] = bf2f((ushort)(pc.y & 0xffff)); ph[11] = bf2f((ushort)(pc.y >> 16));
            #pragma unroll
            for (int h = 0; h < 12; h++) {
                acc[h][0] += ph[h] * zv[u].x;
                acc[h][1] += ph[h] * zv[u].y;
            }
        }
    }
    #pragma unroll
    for (int h = 0; h < 12; h++)
        *(float2*)&pslab[(w * 12 + h) * 128 + c0] = make_float2(acc[h][0], acc[h][1]);
    __syncthreads();

    for (int e = tid; e < 1536; e += 256) {
        float ssum = pslab[e] + pslab[1536 + e] + pslab[3072 + e] + pslab[4608 + e];
        part[((size_t)jq * NN + i) * 1536 + e] = ssum;
    }
}

// ---------------- combine rpair quarters into cat
__global__ void combine_rpair_kernel(const float* __restrict__ part, float* __restrict__ cat)
{
    int v = blockIdx.x * 256 + threadIdx.x;     // 512*1536
    int i = v / 1536, hc = v % 1536;
    int h = hc >> 7, c = hc & 127;
    float ssum = part[(size_t)i * 1536 + hc]
               + part[((size_t)NN + i) * 1536 + hc]
               + part[((size_t)2 * NN + i) * 1536 + hc]
               + part[((size_t)3 * NN + i) * 1536 + hc];
    cat[(size_t)i * CATDIM + h * CATH + 48 + c] = ssum;
}

// ---------------- per-head r_scalar + r_pt (+rotate back, norm); attn bf16
__global__ void head_sum_kernel(const ushort* __restrict__ attn_bf, const float* __restrict__ tmp,
                                const float* __restrict__ rot, const float* __restrict__ tran,
                                float* __restrict__ cat)
{
    int i0 = blockIdx.x * 32;
    int h  = blockIdx.y;
    __shared__ float At[32][65];
    __shared__ float Sr[64][44];
    __shared__ float Rp[32][24];
    int tid = threadIdx.x;
    int il = tid & 31, fg = tid >> 5;
    float acc[5] = {0,0,0,0,0};

    for (int jc = 0; jc < NN; jc += 64) {
        {
            int r = tid >> 3, c8 = (tid & 7) * 8;
            const ushort* src = attn_bf + ((size_t)(i0 + r) * HH + h) * NN + jc + c8;
            BFU v; v.q = *(const uint4*)src;
            #pragma unroll
            for (int q = 0; q < 8; q++) At[r][c8 + q] = bf2f(v.u[q]);
        }
        {
            int jr = tid >> 2, d4 = (tid & 3) * 4;
            *(float4*)&Sr[jr][d4] = *(const float4*)&tmp[(size_t)(jc + jr) * TMPW + 384 + h * 16 + d4];
        }
        for (int e = tid; e < 384; e += 256) {
            int jr = e / 6, p4 = (e % 6) * 4;
            *(float4*)&Sr[jr][16 + p4] = *(const float4*)&tmp[(size_t)(jc + jr) * TMPW + 864 + h * 24 + p4];
        }
        __syncthreads();
        #pragma unroll 4
        for (int j = 0; j < 64; j++) {
            float a = At[il][j];
            #pragma unroll
            for (int q = 0; q < 5; q++) acc[q] += a * Sr[j][fg * 5 + q];
        }
        __syncthreads();
    }

    float* cbase = cat + (size_t)(i0 + il) * CATDIM + h * CATH;
    #pragma unroll
    for (int q = 0; q < 5; q++) {
        int f = fg * 5 + q;
        if (f < 16) cbase[f] = acc[q];
        else Rp[il][f - 16] = acc[q];
    }
    __syncthreads();

    {
        int il2 = tid >> 3, p = tid & 7;
        int i = i0 + il2;
        float gx = Rp[il2][p * 3 + 0] - tran[i * 3 + 0];
        float gy = Rp[il2][p * 3 + 1] - tran[i * 3 + 1];
        float gz = Rp[il2][p * 3 + 2] - tran[i * 3 + 2];
        const float* R = rot + i * 9;
        float lx = R[0] * gx + R[3] * gy + R[6] * gz;
        float ly = R[1] * gx + R[4] * gy + R[7] * gz;
        float lz = R[2] * gx + R[5] * gy + R[8] * gz;
        float nrm = sqrtf(lx * lx + ly * ly + lz * lz + 1e-8f);
        float* cp = cat + (size_t)i * CATDIM + h * CATH;
        cp[16 + p * 3 + 0] = lx; cp[16 + p * 3 + 1] = ly; cp[16 + p * 3 + 2] = lz;
        cp[40 + p] = nrm;
    }
}

// ---------------- out GEMM, K-split
__global__ void out_gemm_split_kernel(const float* __restrict__ cat, const float* __restrict__ Wout,
                                      float* __restrict__ part)
{
    int n0 = blockIdx.x * 64;
    int i0 = blockIdx.y * 64;
    int ks = blockIdx.z * KSPL;
    __shared__ float St[32][68];
    __shared__ float Bs[32][68];
    int tid = threadIdx.x;
    int ty = tid >> 4, tx = tid & 15;
    float acc[4][4] = {{0,0,0,0},{0,0,0,0},{0,0,0,0},{0,0,0,0}};

    for (int k0 = 0; k0 < KSPL; k0 += 32) {
        {
            int r = tid >> 2, c8 = (tid & 3) * 8;
            const float* src = cat + (size_t)(i0 + r) * CATDIM + ks + k0 + c8;
            float4 v0 = *(const float4*)src;
            float4 v1 = *(const float4*)(src + 4);
            St[c8+0][r]=v0.x; St[c8+1][r]=v0.y; St[c8+2][r]=v0.z; St[c8+3][r]=v0.w;
            St[c8+4][r]=v1.x; St[c8+5][r]=v1.y; St[c8+6][r]=v1.z; St[c8+7][r]=v1.w;
        }
        {
            int r = tid >> 3, c8 = (tid & 7) * 8;
            const float* src = Wout + (size_t)(ks + k0 + r) * CSD + n0 + c8;
            *(float4*)&Bs[r][c8]     = *(const float4*)src;
            *(float4*)&Bs[r][c8 + 4] = *(const float4*)(src + 4);
        }
        __syncthreads();
        #pragma unroll
        for (int k = 0; k < 32; k++) {
            float4 a = *(const float4*)&St[k][ty * 4];
            float4 b = *(const float4*)&Bs[k][tx * 4];
            float av[4] = {a.x, a.y, a.z, a.w};
            float bv[4] = {b.x, b.y, b.z, b.w};
            #pragma unroll
            for (int r = 0; r < 4; r++)
                #pragma unroll
                for (int c = 0; c < 4; c++) acc[r][c] += av[r] * bv[c];
        }
        __syncthreads();
    }
    #pragma unroll
    for (int r = 0; r < 4; r++) {
        float4 v = make_float4(acc[r][0], acc[r][1], acc[r][2], acc[r][3]);
        *(float4*)&part[((size_t)blockIdx.z * NN + i0 + ty * 4 + r) * CSD + n0 + tx * 4] = v;
    }
}

__global__ void reduce_out_kernel(const float* __restrict__ part, const float* __restrict__ bout,
                                  float* __restrict__ out)
{
    int v = blockIdx.x * 256 + threadIdx.x;
    int n4 = v % 96;
    float4 o = ((const float4*)bout)[n4];
    const float4* p4 = (const float4*)part;
    #pragma unroll
    for (int s = 0; s < NSPLIT; s++) {
        float4 t = p4[(size_t)s * 49152 + v];
        o.x += t.x; o.y += t.y; o.z += t.z; o.w += t.w;
    }
    ((float4*)out)[v] = o;
}

extern "C" void kernel_launch(void* const* d_in, const int* in_sizes, int n_in,
                              void* d_out, int out_size, void* d_ws, size_t ws_size,
                              hipStream_t stream) {
    const float* s    = (const float*)d_in[0];
    const float* z    = (const float*)d_in[1];
    const float* rot  = (const float*)d_in[2];
    const float* tran = (const float*)d_in[3];
    const float* resm = (const float*)d_in[4];
    const float* Wsq  = (const float*)d_in[5];  const float* bsq = (const float*)d_in[6];
    const float* Wsk  = (const float*)d_in[7];  const float* bsk = (const float*)d_in[8];
    const float* Wsv  = (const float*)d_in[9];  const float* bsv = (const float*)d_in[10];
    const float* Wsb  = (const float*)d_in[11]; const float* bsb = (const float*)d_in[12];
    const float* Wpq  = (const float*)d_in[13]; const float* bpq = (const float*)d_in[14];
    const float* Wpk  = (const float*)d_in[15]; const float* bpk = (const float*)d_in[16];
    const float* Wpv  = (const float*)d_in[17]; const float* bpv = (const float*)d_in[18];
    const float* watt = (const float*)d_in[19]; const float* batt = (const float*)d_in[20];
    const float* tpw  = (const float*)d_in[21];
    const float* Wout = (const float*)d_in[22]; const float* bout = (const float*)d_in[23];
    float* out = (float*)d_out;
    float* ws  = (float*)d_ws;

    float*  tmp     = ws;                        // 589824 floats
    ushort* attn_bf = (ushort*)(ws + 589824);    // 3145728 ushorts (1572864 f-slots)
    float*  lgts    = ws + 589824 + 1572864;     // 3145728 floats
    float*  partR   = lgts + 3145728;            // 4*512*1536 = 3145728 floats
    float*  cat     = partR + 3145728;           // 1081344 floats
    float*  partO   = cat + 1081344;             // 1179648 floats

    proj_gemm_kernel<<<dim3(24, 16), 256, 0, stream>>>(s, rot, tran,
                                                       Wsq, bsq, Wsk, bsk, Wsv, bsv,
                                                       Wpq, bpq, Wpk, bpk, Wpv, bpv, tmp);
    logits_kernel<<<dim3(4, 512), 256, 0, stream>>>(z, resm, Wsb, bsb, watt, batt,
                                                    tpw, tmp, lgts);
    softmax_kernel<<<1536, 256, 0, stream>>>(lgts, attn_bf);
    rpair_kernel<<<dim3(4, 512), 256, 0, stream>>>(z, attn_bf, partR);
    combine_rpair_kernel<<<3072, 256, 0, stream>>>(partR, cat);
    head_sum_kernel<<<dim3(16, 12), 256, 0, stream>>>(attn_bf, tmp, rot, tran, cat);
    out_gemm_split_kernel<<<dim3(6, 8, NSPLIT), 256, 0, stream>>>(cat, Wout, partO);
    reduce_out_kernel<<<192, 256, 0, stream>>>(partO, bout, out);
}

// Round 13
// 184.343 us; speedup vs baseline: 1.4487x; 1.0874x over previous
//
#include <hip/hip_runtime.h>
#include <hip/hip_bf16.h>
#include <math.h>

#define NN 512
#define CSD 384
#define CZ 128
#define HH 12
#define TMPW 1152          // 192 sq | 192 sk | 192 sv | 144 pq | 144 pk | 288 pv
#define CATH 176
#define CATDIM 2112
#define NSPLIT 6
#define KSPL 352

#define SW 0.14433756729740643f
#define PW 0.13608276348795434f
#define ZW 0.57735026918962576f
#define NEG_INF -3.4028234663852886e38f

typedef float f32x4_t __attribute__((ext_vector_type(4)));
typedef short bf16x8_t __attribute__((ext_vector_type(8)));

union BFU { uint4 q; bf16x8_t v; ushort u[8]; };

static __device__ __forceinline__ ushort f2bf(float f) {
    __hip_bfloat16 h = __float2bfloat16(f);
    return *reinterpret_cast<ushort*>(&h);
}
static __device__ __forceinline__ float bf2f(ushort u) {
    unsigned int v = ((unsigned int)u) << 16;
    return __uint_as_float(v);
}

// ---------------- proj GEMM + fused rotation: tmp[512][1152] = s @ Wcat + bias
__global__ void proj_gemm_kernel(const float* __restrict__ s, const float* __restrict__ rot,
                                 const float* __restrict__ tran,
                                 const float* __restrict__ Wsq, const float* __restrict__ bsq,
                                 const float* __restrict__ Wsk, const float* __restrict__ bsk,
                                 const float* __restrict__ Wsv, const float* __restrict__ bsv,
                                 const float* __restrict__ Wpq, const float* __restrict__ bpq,
                                 const float* __restrict__ Wpk, const float* __restrict__ bpk,
                                 const float* __restrict__ Wpv, const float* __restrict__ bpv,
                                 float* __restrict__ tmp)
{
    int bx = blockIdx.x;            // 24 f-tiles of 48
    int n0 = blockIdx.y * 32;       // 16 n-tiles
    int f0 = bx * 48;
    const float* W; const float* bb; int dout; int segstart;
    if (bx < 4)       { W = Wsq; bb = bsq; dout = 192; segstart = 0; }
    else if (bx < 8)  { W = Wsk; bb = bsk; dout = 192; segstart = 192; }
    else if (bx < 12) { W = Wsv; bb = bsv; dout = 192; segstart = 384; }
    else if (bx < 15) { W = Wpq; bb = bpq; dout = 144; segstart = 576; }
    else if (bx < 18) { W = Wpk; bb = bpk; dout = 144; segstart = 720; }
    else              { W = Wpv; bb = bpv; dout = 288; segstart = 864; }
    int colbase = f0 - segstart;

    __shared__ float St[32][34];
    __shared__ float Ws[32][49];
    int tid = threadIdx.x;
    int ty = tid >> 4, tx = tid & 15;
    float acc[2][3] = {{0,0,0},{0,0,0}};

    for (int k0 = 0; k0 < CSD; k0 += 32) {
        {
            int r = tid >> 3, c4 = (tid & 7) * 4;
            float4 v = *(const float4*)&s[(size_t)(n0 + r) * CSD + k0 + c4];
            St[c4 + 0][r] = v.x; St[c4 + 1][r] = v.y; St[c4 + 2][r] = v.z; St[c4 + 3][r] = v.w;
        }
        for (int e = tid; e < 1536; e += 256) {
            int r = e / 48, c = e % 48;
            Ws[r][c] = W[(size_t)(k0 + r) * dout + colbase + c];
        }
        __syncthreads();
        #pragma unroll
        for (int k = 0; k < 32; k++) {
            float2 a = *(const float2*)&St[k][ty * 2];
            float b0 = Ws[k][tx * 3], b1 = Ws[k][tx * 3 + 1], b2 = Ws[k][tx * 3 + 2];
            acc[0][0] += a.x * b0; acc[0][1] += a.x * b1; acc[0][2] += a.x * b2;
            acc[1][0] += a.y * b0; acc[1][1] += a.y * b1; acc[1][2] += a.y * b2;
        }
        __syncthreads();
    }
    float bv0 = bb[colbase + tx * 3], bv1 = bb[colbase + tx * 3 + 1], bv2 = bb[colbase + tx * 3 + 2];
    #pragma unroll
    for (int r = 0; r < 2; r++) {
        int n = n0 + ty * 2 + r;
        float v0 = acc[r][0] + bv0, v1 = acc[r][1] + bv1, v2 = acc[r][2] + bv2;
        float* o = tmp + (size_t)n * TMPW + f0 + tx * 3;
        if (bx >= 12) {
            const float* R = rot + n * 9;
            const float* T = tran + n * 3;
            float g0 = R[0] * v0 + R[1] * v1 + R[2] * v2 + T[0];
            float g1 = R[3] * v0 + R[4] * v1 + R[5] * v2 + T[1];
            float g2 = R[6] * v0 + R[7] * v1 + R[8] * v2 + T[2];
            o[0] = g0; o[1] = g1; o[2] = g2;
        } else {
            o[0] = v0; o[1] = v1; o[2] = v2;
        }
    }
}

// ---------------- augprep: build Qaug/Kaug [h][n][32] bf16 from tmp.
// logit = Qaug . Kaug + pair:  [16 sq*SW*w0 | 12 -2cpt*pq | cpt|pq|^2, cpt | cb, 0]
//                           x  [16 sk      | 12 pk       | 1, |pk|^2   | 1,  0]
__global__ void augprep_kernel(const float* __restrict__ tmp,
                               const float* __restrict__ watt, const float* __restrict__ batt,
                               const float* __restrict__ tpw, const float* __restrict__ bsb,
                               ushort* __restrict__ Qaug, ushort* __restrict__ Kaug)
{
    int n = blockIdx.x;
    int tid = threadIdx.x;
    float w0 = watt[0], w1 = watt[1], w2 = watt[2], ba = batt[0];
    float A2 = w2 * ZW;
    __shared__ float nq[12], nk[12];
    if (tid < 24) {
        int h = tid >> 1, which = tid & 1;
        const float* p = tmp + (size_t)n * TMPW + (which ? 720 : 576) + h * 12;
        float s2 = 0.f;
        #pragma unroll
        for (int d = 0; d < 12; d++) s2 += p[d] * p[d];
        if (which) nk[h] = s2; else nq[h] = s2;
    }
    __syncthreads();

    for (int f = tid; f < 384; f += 256) {
        if (f < 192) {
            int h = f >> 4, k = f & 15;
            float sq = tmp[(size_t)n * TMPW + h * 16 + k] * (SW * w0);
            float sk = tmp[(size_t)n * TMPW + 192 + h * 16 + k];
            Qaug[((size_t)h * NN + n) * 32 + k] = f2bf(sq);
            Kaug[((size_t)h * NN + n) * 32 + k] = f2bf(sk);
        } else if (f < 336) {
            int e = f - 192; int h = e / 12, d = e % 12;
            float cpt = -0.5f * log1pf(expf(tpw[h])) * PW * w1;
            float pq = tmp[(size_t)n * TMPW + 576 + h * 12 + d];
            float pk = tmp[(size_t)n * TMPW + 720 + h * 12 + d];
            Qaug[((size_t)h * NN + n) * 32 + 16 + d] = f2bf(-2.f * cpt * pq);
            Kaug[((size_t)h * NN + n) * 32 + 16 + d] = f2bf(pk);
        } else {
            int e = f - 336; int h = e >> 2, sl = e & 3;
            float cpt = -0.5f * log1pf(expf(tpw[h])) * PW * w1;
            float qv, kv;
            if (sl == 0)      { qv = cpt * nq[h];      kv = 1.f; }
            else if (sl == 1) { qv = cpt;              kv = nk[h]; }
            else if (sl == 2) { qv = A2 * bsb[h] + ba; kv = 1.f; }
            else              { qv = 0.f;              kv = 0.f; }
            Qaug[((size_t)h * NN + n) * 32 + 28 + sl] = f2bf(qv);
            Kaug[((size_t)h * NN + n) * 32 + 28 + sl] = f2bf(kv);
        }
    }
}

// ---------------- zlogits: PURE z-stream pair-bias via register MFMA.
// grid (4 jc, 512 i), block 256; no LDS, no gathers. Writes lgts f32 [i][h][j].
__global__ __launch_bounds__(256) void zlogits_kernel(const float* __restrict__ z,
                                                      const float* __restrict__ resm,
                                                      const float* __restrict__ Wsb,
                                                      const float* __restrict__ watt,
                                                      float* __restrict__ lgts)
{
    int jc = blockIdx.x;
    int i  = blockIdx.y;
    int tid = threadIdx.x;
    int w = tid >> 6, lane = tid & 63;
    int l16 = lane & 15, lhi = lane >> 4;
    float A2 = watt[2] * ZW;

    BFU breg[4];
    #pragma unroll
    for (int kk = 0; kk < 4; kk++) {
        #pragma unroll
        for (int e = 0; e < 8; e++) {
            int k = kk * 32 + lhi * 8 + e;
            float v = (l16 < HH) ? Wsb[k * HH + l16] * A2 : 0.f;
            breg[kk].u[e] = f2bf(v);
        }
    }

    const float* zi = z + (size_t)i * NN * CZ;
    float rmi = resm[i];

    #pragma unroll
    for (int t = 0; t < 2; t++) {
        int jbase = jc * 128 + (w * 2 + t) * 16;
        const float* zr = zi + (size_t)(jbase + l16) * CZ + lhi * 8;
        float4 pr[8];
        #pragma unroll
        for (int kk = 0; kk < 4; kk++) {
            pr[kk * 2]     = *(const float4*)&zr[kk * 32];
            pr[kk * 2 + 1] = *(const float4*)&zr[kk * 32 + 4];
        }
        f32x4_t acc = {0.f, 0.f, 0.f, 0.f};
        #pragma unroll
        for (int kk = 0; kk < 4; kk++) {
            float4 f0 = pr[kk * 2], f1 = pr[kk * 2 + 1];
            BFU a;
            a.u[0] = f2bf(f0.x); a.u[1] = f2bf(f0.y); a.u[2] = f2bf(f0.z); a.u[3] = f2bf(f0.w);
            a.u[4] = f2bf(f1.x); a.u[5] = f2bf(f1.y); a.u[6] = f2bf(f1.z); a.u[7] = f2bf(f1.w);
            acc = __builtin_amdgcn_mfma_f32_16x16x32_bf16(a.v, breg[kk].v, acc, 0, 0, 0);
        }
        if (l16 < HH) {
            #pragma unroll
            for (int r = 0; r < 4; r++) {
                int j = jbase + lhi * 4 + r;
                float mj = rmi * resm[j];
                float lg = acc[r];
                if (mj == 0.f) lg = NEG_INF;
                lgts[((size_t)i * HH + l16) * NN + j] = lg;
            }
        }
    }
}

// ---------------- augsm: aug-GEMM (scalar+point+cb) + add pair lgts + softmax.
// grid (32 i-tiles of 16, 12 h), block 256.
__global__ __launch_bounds__(256) void augsm_kernel(const float* __restrict__ lgts,
                                                    const ushort* __restrict__ Qaug,
                                                    const ushort* __restrict__ Kaug,
                                                    ushort* __restrict__ attn_bf)
{
    int it = blockIdx.x;        // i-tile
    int h  = blockIdx.y;
    __shared__ float Dt[16][520];   // 33.3 KB
    int tid = threadIdx.x;
    int w = tid >> 6, lane = tid & 63;
    int l16 = lane & 15, lhi = lane >> 4;

    BFU a;
    a.q = *(const uint4*)&Qaug[(((size_t)h * NN) + it * 16 + l16) * 32 + lhi * 8];

    for (int jt = w; jt < 32; jt += 4) {
        BFU b;
        b.q = *(const uint4*)&Kaug[(((size_t)h * NN) + jt * 16 + l16) * 32 + lhi * 8];
        f32x4_t acc = {0.f, 0.f, 0.f, 0.f};
        acc = __builtin_amdgcn_mfma_f32_16x16x32_bf16(a.v, b.v, acc, 0, 0, 0);
        #pragma unroll
        for (int r = 0; r < 4; r++) Dt[lhi * 4 + r][jt * 16 + l16] = acc[r];
    }
    __syncthreads();

    #pragma unroll
    for (int rr = 0; rr < 4; rr++) {
        int row = w * 4 + rr;
        const float* lrow = lgts + (((size_t)(it * 16 + row)) * HH + h) * NN;
        float v[8]; float m = -INFINITY;
        #pragma unroll
        for (int u = 0; u < 8; u++) {
            v[u] = lrow[lane + 64 * u] + Dt[row][lane + 64 * u];
            m = fmaxf(m, v[u]);
        }
        for (int off = 32; off; off >>= 1) m = fmaxf(m, __shfl_xor(m, off));
        float ssum = 0.f;
        #pragma unroll
        for (int u = 0; u < 8; u++) { v[u] = __expf(v[u] - m); ssum += v[u]; }
        for (int off = 32; off; off >>= 1) ssum += __shfl_xor(ssum, off);
        float inv = 1.f / ssum;
        ushort* ag = attn_bf + (((size_t)(it * 16 + row)) * HH + h) * NN;
        #pragma unroll
        for (int u = 0; u < 8; u++) ag[lane + 64 * u] = f2bf(v[u] * inv);
    }
}

// ---------------- rpair partials: grid (4 jq, 512 i), block 256; 16-deep unroll.
__global__ __launch_bounds__(256) void rpair_kernel(const float* __restrict__ z,
                                                    const ushort* __restrict__ attn_bf,
                                                    float* __restrict__ part)
{
    int jq = blockIdx.x;
    int i  = blockIdx.y;
    __shared__ ushort pbf[128 * 12];
    __shared__ float pslab[4 * 12 * 128];
    int tid = threadIdx.x;

    if (tid < 192) {
        int h = tid >> 4, g = tid & 15;
        BFU v; v.q = *(const uint4*)&attn_bf[((size_t)i * HH + h) * NN + jq * 128 + g * 8];
        #pragma unroll
        for (int q = 0; q < 8; q++) pbf[(g * 8 + q) * 12 + h] = v.u[q];
    }
    __syncthreads();

    int w = tid >> 6, lane = tid & 63;
    int c0 = lane * 2;
    const float* zq = z + ((size_t)i * NN + jq * 128 + w * 32) * CZ + c0;
    float acc[12][2];
    #pragma unroll
    for (int h = 0; h < 12; h++) { acc[h][0] = 0.f; acc[h][1] = 0.f; }

    #pragma unroll
    for (int j0 = 0; j0 < 32; j0 += 16) {
        float2 zv[16];
        #pragma unroll
        for (int u = 0; u < 16; u++) zv[u] = *(const float2*)&zq[(size_t)(j0 + u) * CZ];
        #pragma unroll
        for (int u = 0; u < 16; u++) {
            int jl = w * 32 + j0 + u;
            const uint2* pr = (const uint2*)&pbf[jl * 12];
            uint2 pa = pr[0], pb2 = pr[1], pc = pr[2];
            float ph[12];
            ph[0]  = bf2f((ushort)(pa.x & 0xffff)); ph[1]  = bf2f((ushort)(pa.x >> 16));
            ph[2]  = bf2f((ushort)(pa.y & 0xffff)); ph[3]  = bf2f((ushort)(pa.y >> 16));
            ph[4]  = bf2f((ushort)(pb2.x & 0xffff)); ph[5]  = bf2f((ushort)(pb2.x >> 16));
            ph[6]  = bf2f((ushort)(pb2.y & 0xffff)); ph[7]  = bf2f((ushort)(pb2.y >> 16));
            ph[8]  = bf2f((ushort)(pc.x & 0xffff)); ph[9]  = bf2f((ushort)(pc.x >> 16));
            ph[10] = bf2f((ushort)(pc.y & 0xffff)); ph[11] = bf2f((ushort)(pc.y >> 16));
            #pragma unroll
            for (int h = 0; h < 12; h++) {
                acc[h][0] += ph[h] * zv[u].x;
                acc[h][1] += ph[h] * zv[u].y;
            }
        }
    }
    #pragma unroll
    for (int h = 0; h < 12; h++)
        *(float2*)&pslab[(w * 12 + h) * 128 + c0] = make_float2(acc[h][0], acc[h][1]);
    __syncthreads();

    for (int e = tid; e < 1536; e += 256) {
        float ssum = pslab[e] + pslab[1536 + e] + pslab[3072 + e] + pslab[4608 + e];
        part[((size_t)jq * NN + i) * 1536 + e] = ssum;
    }
}

// ---------------- combine rpair quarters into cat
__global__ void combine_rpair_kernel(const float* __restrict__ part, float* __restrict__ cat)
{
    int v = blockIdx.x * 256 + threadIdx.x;
    int i = v / 1536, hc = v % 1536;
    int h = hc >> 7, c = hc & 127;
    float ssum = part[(size_t)i * 1536 + hc]
               + part[((size_t)NN + i) * 1536 + hc]
               + part[((size_t)2 * NN + i) * 1536 + hc]
               + part[((size_t)3 * NN + i) * 1536 + hc];
    cat[(size_t)i * CATDIM + h * CATH + 48 + c] = ssum;
}

// ---------------- per-head r_scalar + r_pt (+rotate back, norm); attn bf16
__global__ void head_sum_kernel(const ushort* __restrict__ attn_bf, const float* __restrict__ tmp,
                                const float* __restrict__ rot, const float* __restrict__ tran,
                                float* __restrict__ cat)
{
    int i0 = blockIdx.x * 32;
    int h  = blockIdx.y;
    __shared__ float At[32][65];
    __shared__ float Sr[64][44];
    __shared__ float Rp[32][24];
    int tid = threadIdx.x;
    int il = tid & 31, fg = tid >> 5;
    float acc[5] = {0,0,0,0,0};

    for (int jc = 0; jc < NN; jc += 64) {
        {
            int r = tid >> 3, c8 = (tid & 7) * 8;
            const ushort* src = attn_bf + ((size_t)(i0 + r) * HH + h) * NN + jc + c8;
            BFU v; v.q = *(const uint4*)src;
            #pragma unroll
            for (int q = 0; q < 8; q++) At[r][c8 + q] = bf2f(v.u[q]);
        }
        {
            int jr = tid >> 2, d4 = (tid & 3) * 4;
            *(float4*)&Sr[jr][d4] = *(const float4*)&tmp[(size_t)(jc + jr) * TMPW + 384 + h * 16 + d4];
        }
        for (int e = tid; e < 384; e += 256) {
            int jr = e / 6, p4 = (e % 6) * 4;
            *(float4*)&Sr[jr][16 + p4] = *(const float4*)&tmp[(size_t)(jc + jr) * TMPW + 864 + h * 24 + p4];
        }
        __syncthreads();
        #pragma unroll 4
        for (int j = 0; j < 64; j++) {
            float a = At[il][j];
            #pragma unroll
            for (int q = 0; q < 5; q++) acc[q] += a * Sr[j][fg * 5 + q];
        }
        __syncthreads();
    }

    float* cbase = cat + (size_t)(i0 + il) * CATDIM + h * CATH;
    #pragma unroll
    for (int q = 0; q < 5; q++) {
        int f = fg * 5 + q;
        if (f < 16) cbase[f] = acc[q];
        else Rp[il][f - 16] = acc[q];
    }
    __syncthreads();

    {
        int il2 = tid >> 3, p = tid & 7;
        int i = i0 + il2;
        float gx = Rp[il2][p * 3 + 0] - tran[i * 3 + 0];
        float gy = Rp[il2][p * 3 + 1] - tran[i * 3 + 1];
        float gz = Rp[il2][p * 3 + 2] - tran[i * 3 + 2];
        const float* R = rot + i * 9;
        float lx = R[0] * gx + R[3] * gy + R[6] * gz;
        float ly = R[1] * gx + R[4] * gy + R[7] * gz;
        float lz = R[2] * gx + R[5] * gy + R[8] * gz;
        float nrm = sqrtf(lx * lx + ly * ly + lz * lz + 1e-8f);
        float* cp = cat + (size_t)i * CATDIM + h * CATH;
        cp[16 + p * 3 + 0] = lx; cp[16 + p * 3 + 1] = ly; cp[16 + p * 3 + 2] = lz;
        cp[40 + p] = nrm;
    }
}

// ---------------- out GEMM, K-split
__global__ void out_gemm_split_kernel(const float* __restrict__ cat, const float* __restrict__ Wout,
                                      float* __restrict__ part)
{
    int n0 = blockIdx.x * 64;
    int i0 = blockIdx.y * 64;
    int ks = blockIdx.z * KSPL;
    __shared__ float St[32][68];
    __shared__ float Bs[32][68];
    int tid = threadIdx.x;
    int ty = tid >> 4, tx = tid & 15;
    float acc[4][4] = {{0,0,0,0},{0,0,0,0},{0,0,0,0},{0,0,0,0}};

    for (int k0 = 0; k0 < KSPL; k0 += 32) {
        {
            int r = tid >> 2, c8 = (tid & 3) * 8;
            const float* src = cat + (size_t)(i0 + r) * CATDIM + ks + k0 + c8;
            float4 v0 = *(const float4*)src;
            float4 v1 = *(const float4*)(src + 4);
            St[c8+0][r]=v0.x; St[c8+1][r]=v0.y; St[c8+2][r]=v0.z; St[c8+3][r]=v0.w;
            St[c8+4][r]=v1.x; St[c8+5][r]=v1.y; St[c8+6][r]=v1.z; St[c8+7][r]=v1.w;
        }
        {
            int r = tid >> 3, c8 = (tid & 7) * 8;
            const float* src = Wout + (size_t)(ks + k0 + r) * CSD + n0 + c8;
            *(float4*)&Bs[r][c8]     = *(const float4*)src;
            *(float4*)&Bs[r][c8 + 4] = *(const float4*)(src + 4);
        }
        __syncthreads();
        #pragma unroll
        for (int k = 0; k < 32; k++) {
            float4 a = *(const float4*)&St[k][ty * 4];
            float4 b = *(const float4*)&Bs[k][tx * 4];
            float av[4] = {a.x, a.y, a.z, a.w};
            float bv[4] = {b.x, b.y, b.z, b.w};
            #pragma unroll
            for (int r = 0; r < 4; r++)
                #pragma unroll
                for (int c = 0; c < 4; c++) acc[r][c] += av[r] * bv[c];
        }
        __syncthreads();
    }
    #pragma unroll
    for (int r = 0; r < 4; r++) {
        float4 v = make_float4(acc[r][0], acc[r][1], acc[r][2], acc[r][3]);
        *(float4*)&part[((size_t)blockIdx.z * NN + i0 + ty * 4 + r) * CSD + n0 + tx * 4] = v;
    }
}

__global__ void reduce_out_kernel(const float* __restrict__ part, const float* __restrict__ bout,
                                  float* __restrict__ out)
{
    int v = blockIdx.x * 256 + threadIdx.x;
    int n4 = v % 96;
    float4 o = ((const float4*)bout)[n4];
    const float4* p4 = (const float4*)part;
    #pragma unroll
    for (int s = 0; s < NSPLIT; s++) {
        float4 t = p4[(size_t)s * 49152 + v];
        o.x += t.x; o.y += t.y; o.z += t.z; o.w += t.w;
    }
    ((float4*)out)[v] = o;
}

extern "C" void kernel_launch(void* const* d_in, const int* in_sizes, int n_in,
                              void* d_out, int out_size, void* d_ws, size_t ws_size,
                              hipStream_t stream) {
    const float* s    = (const float*)d_in[0];
    const float* z    = (const float*)d_in[1];
    const float* rot  = (const float*)d_in[2];
    const float* tran = (const float*)d_in[3];
    const float* resm = (const float*)d_in[4];
    const float* Wsq  = (const float*)d_in[5];  const float* bsq = (const float*)d_in[6];
    const float* Wsk  = (const float*)d_in[7];  const float* bsk = (const float*)d_in[8];
    const float* Wsv  = (const float*)d_in[9];  const float* bsv = (const float*)d_in[10];
    const float* Wsb  = (const float*)d_in[11]; const float* bsb = (const float*)d_in[12];
    const float* Wpq  = (const float*)d_in[13]; const float* bpq = (const float*)d_in[14];
    const float* Wpk  = (const float*)d_in[15]; const float* bpk = (const float*)d_in[16];
    const float* Wpv  = (const float*)d_in[17]; const float* bpv = (const float*)d_in[18];
    const float* watt = (const float*)d_in[19]; const float* batt = (const float*)d_in[20];
    const float* tpw  = (const float*)d_in[21];
    const float* Wout = (const float*)d_in[22]; const float* bout = (const float*)d_in[23];
    float* out = (float*)d_out;
    float* ws  = (float*)d_ws;

    float*  tmp     = ws;                        // 589824
    ushort* attn_bf = (ushort*)(ws + 589824);    // 1572864 f-slots
    float*  lgts    = ws + 2162688;              // 3145728
    float*  partR   = ws + 5308416;              // 3145728
    ushort* Qaug    = (ushort*)(ws + 8454144);   // 98304 f-slots
    ushort* Kaug    = (ushort*)(ws + 8552448);   // 98304 f-slots
    float*  cat     = ws + 8650752;              // 1081344
    float*  partO   = ws + 9732096;              // 1179648

    proj_gemm_kernel<<<dim3(24, 16), 256, 0, stream>>>(s, rot, tran,
                                                       Wsq, bsq, Wsk, bsk, Wsv, bsv,
                                                       Wpq, bpq, Wpk, bpk, Wpv, bpv, tmp);
    augprep_kernel<<<512, 256, 0, stream>>>(tmp, watt, batt, tpw, bsb, Qaug, Kaug);
    zlogits_kernel<<<dim3(4, 512), 256, 0, stream>>>(z, resm, Wsb, watt, lgts);
    augsm_kernel<<<dim3(32, 12), 256, 0, stream>>>(lgts, Qaug, Kaug, attn_bf);
    rpair_kernel<<<dim3(4, 512), 256, 0, stream>>>(z, attn_bf, partR);
    combine_rpair_kernel<<<3072, 256, 0, stream>>>(partR, cat);
    head_sum_kernel<<<dim3(16, 12), 256, 0, stream>>>(attn_bf, tmp, rot, tran, cat);
    out_gemm_split_kernel<<<dim3(6, 8, NSPLIT), 256, 0, stream>>>(cat, Wout, partO);
    reduce_out_kernel<<<192, 256, 0, stream>>>(partO, bout, out);
}

// Round 14
// 182.887 us; speedup vs baseline: 1.4602x; 1.0080x over previous
//
#include <hip/hip_runtime.h>
#include <hip/hip_bf16.h>
#include <math.h>

#define NN 512
#define CSD 384
#define CZ 128
#define HH 12
#define TMPW 1152          // 192 sq | 192 sk | 192 sv | 144 pq | 144 pk | 288 pv
#define CATH 176
#define CATDIM 2112
#define NSPLIT 6
#define KSPL 352

#define SW 0.14433756729740643f
#define PW 0.13608276348795434f
#define ZW 0.57735026918962576f
#define NEG_INF -3.4028234663852886e38f
#define MASK_NEG -1.0e30f

typedef float f32x4_t __attribute__((ext_vector_type(4)));
typedef short bf16x8_t __attribute__((ext_vector_type(8)));

union BFU { uint4 q; bf16x8_t v; ushort u[8]; };
union US4 { ushort us[4]; uint2 u2; };

static __device__ __forceinline__ ushort f2bf(float f) {
    __hip_bfloat16 h = __float2bfloat16(f);
    return *reinterpret_cast<ushort*>(&h);
}
static __device__ __forceinline__ float bf2f(ushort u) {
    unsigned int v = ((unsigned int)u) << 16;
    return __uint_as_float(v);
}

// ---------------- proj GEMM + fused rotation: tmp[512][1152] = s @ Wcat + bias
__global__ void proj_gemm_kernel(const float* __restrict__ s, const float* __restrict__ rot,
                                 const float* __restrict__ tran,
                                 const float* __restrict__ Wsq, const float* __restrict__ bsq,
                                 const float* __restrict__ Wsk, const float* __restrict__ bsk,
                                 const float* __restrict__ Wsv, const float* __restrict__ bsv,
                                 const float* __restrict__ Wpq, const float* __restrict__ bpq,
                                 const float* __restrict__ Wpk, const float* __restrict__ bpk,
                                 const float* __restrict__ Wpv, const float* __restrict__ bpv,
                                 float* __restrict__ tmp)
{
    int bx = blockIdx.x;            // 24 f-tiles of 48
    int n0 = blockIdx.y * 32;       // 16 n-tiles
    int f0 = bx * 48;
    const float* W; const float* bb; int dout; int segstart;
    if (bx < 4)       { W = Wsq; bb = bsq; dout = 192; segstart = 0; }
    else if (bx < 8)  { W = Wsk; bb = bsk; dout = 192; segstart = 192; }
    else if (bx < 12) { W = Wsv; bb = bsv; dout = 192; segstart = 384; }
    else if (bx < 15) { W = Wpq; bb = bpq; dout = 144; segstart = 576; }
    else if (bx < 18) { W = Wpk; bb = bpk; dout = 144; segstart = 720; }
    else              { W = Wpv; bb = bpv; dout = 288; segstart = 864; }
    int colbase = f0 - segstart;

    __shared__ float St[32][34];
    __shared__ float Ws[32][49];
    int tid = threadIdx.x;
    int ty = tid >> 4, tx = tid & 15;
    float acc[2][3] = {{0,0,0},{0,0,0}};

    for (int k0 = 0; k0 < CSD; k0 += 32) {
        {
            int r = tid >> 3, c4 = (tid & 7) * 4;
            float4 v = *(const float4*)&s[(size_t)(n0 + r) * CSD + k0 + c4];
            St[c4 + 0][r] = v.x; St[c4 + 1][r] = v.y; St[c4 + 2][r] = v.z; St[c4 + 3][r] = v.w;
        }
        for (int e = tid; e < 1536; e += 256) {
            int r = e / 48, c = e % 48;
            Ws[r][c] = W[(size_t)(k0 + r) * dout + colbase + c];
        }
        __syncthreads();
        #pragma unroll
        for (int k = 0; k < 32; k++) {
            float2 a = *(const float2*)&St[k][ty * 2];
            float b0 = Ws[k][tx * 3], b1 = Ws[k][tx * 3 + 1], b2 = Ws[k][tx * 3 + 2];
            acc[0][0] += a.x * b0; acc[0][1] += a.x * b1; acc[0][2] += a.x * b2;
            acc[1][0] += a.y * b0; acc[1][1] += a.y * b1; acc[1][2] += a.y * b2;
        }
        __syncthreads();
    }
    float bv0 = bb[colbase + tx * 3], bv1 = bb[colbase + tx * 3 + 1], bv2 = bb[colbase + tx * 3 + 2];
    #pragma unroll
    for (int r = 0; r < 2; r++) {
        int n = n0 + ty * 2 + r;
        float v0 = acc[r][0] + bv0, v1 = acc[r][1] + bv1, v2 = acc[r][2] + bv2;
        float* o = tmp + (size_t)n * TMPW + f0 + tx * 3;
        if (bx >= 12) {
            const float* R = rot + n * 9;
            const float* T = tran + n * 3;
            float g0 = R[0] * v0 + R[1] * v1 + R[2] * v2 + T[0];
            float g1 = R[3] * v0 + R[4] * v1 + R[5] * v2 + T[1];
            float g2 = R[6] * v0 + R[7] * v1 + R[8] * v2 + T[2];
            o[0] = g0; o[1] = g1; o[2] = g2;
        } else {
            o[0] = v0; o[1] = v1; o[2] = v2;
        }
    }
}

// ---------------- augprep: build Qaug/Kaug [h][n][32] bf16 from tmp.
__global__ void augprep_kernel(const float* __restrict__ tmp,
                               const float* __restrict__ watt, const float* __restrict__ batt,
                               const float* __restrict__ tpw, const float* __restrict__ bsb,
                               ushort* __restrict__ Qaug, ushort* __restrict__ Kaug)
{
    int n = blockIdx.x;
    int tid = threadIdx.x;
    float w0 = watt[0], w1 = watt[1], w2 = watt[2], ba = batt[0];
    float A2 = w2 * ZW;
    __shared__ float nq[12], nk[12];
    if (tid < 24) {
        int h = tid >> 1, which = tid & 1;
        const float* p = tmp + (size_t)n * TMPW + (which ? 720 : 576) + h * 12;
        float s2 = 0.f;
        #pragma unroll
        for (int d = 0; d < 12; d++) s2 += p[d] * p[d];
        if (which) nk[h] = s2; else nq[h] = s2;
    }
    __syncthreads();

    for (int f = tid; f < 384; f += 256) {
        if (f < 192) {
            int h = f >> 4, k = f & 15;
            float sq = tmp[(size_t)n * TMPW + h * 16 + k] * (SW * w0);
            float sk = tmp[(size_t)n * TMPW + 192 + h * 16 + k];
            Qaug[((size_t)h * NN + n) * 32 + k] = f2bf(sq);
            Kaug[((size_t)h * NN + n) * 32 + k] = f2bf(sk);
        } else if (f < 336) {
            int e = f - 192; int h = e / 12, d = e % 12;
            float cpt = -0.5f * log1pf(expf(tpw[h])) * PW * w1;
            float pq = tmp[(size_t)n * TMPW + 576 + h * 12 + d];
            float pk = tmp[(size_t)n * TMPW + 720 + h * 12 + d];
            Qaug[((size_t)h * NN + n) * 32 + 16 + d] = f2bf(-2.f * cpt * pq);
            Kaug[((size_t)h * NN + n) * 32 + 16 + d] = f2bf(pk);
        } else {
            int e = f - 336; int h = e >> 2, sl = e & 3;
            float cpt = -0.5f * log1pf(expf(tpw[h])) * PW * w1;
            float qv, kv;
            if (sl == 0)      { qv = cpt * nq[h];      kv = 1.f; }
            else if (sl == 1) { qv = cpt;              kv = nk[h]; }
            else if (sl == 2) { qv = A2 * bsb[h] + ba; kv = 1.f; }
            else              { qv = 0.f;              kv = 0.f; }
            Qaug[((size_t)h * NN + n) * 32 + 28 + sl] = f2bf(qv);
            Kaug[((size_t)h * NN + n) * 32 + 28 + sl] = f2bf(kv);
        }
    }
}

// ---------------- zlogits: pure z-stream pair-bias via register MFMA.
// 16-load-deep pipeline (both tiles loaded before compute). Writes lgts bf16.
__global__ __launch_bounds__(256) void zlogits_kernel(const float* __restrict__ z,
                                                      const float* __restrict__ resm,
                                                      const float* __restrict__ Wsb,
                                                      const float* __restrict__ watt,
                                                      ushort* __restrict__ lgts_bf)
{
    int jc = blockIdx.x;
    int i  = blockIdx.y;
    int tid = threadIdx.x;
    int w = tid >> 6, lane = tid & 63;
    int l16 = lane & 15, lhi = lane >> 4;
    float A2 = watt[2] * ZW;

    BFU breg[4];
    #pragma unroll
    for (int kk = 0; kk < 4; kk++) {
        #pragma unroll
        for (int e = 0; e < 8; e++) {
            int k = kk * 32 + lhi * 8 + e;
            float v = (l16 < HH) ? Wsb[k * HH + l16] * A2 : 0.f;
            breg[kk].u[e] = f2bf(v);
        }
    }

    const float* zi = z + (size_t)i * NN * CZ;
    float rmi = resm[i];
    int jbase = jc * 128 + w * 32;      // wave owns rows jbase..jbase+31

    // issue ALL 16 loads (16 KB/wave in flight) before any compute
    const float* zr0 = zi + (size_t)(jbase + l16) * CZ + lhi * 8;
    const float* zr1 = zi + (size_t)(jbase + 16 + l16) * CZ + lhi * 8;
    float4 pr[16];
    #pragma unroll
    for (int kk = 0; kk < 4; kk++) {
        pr[kk * 2]     = *(const float4*)&zr0[kk * 32];
        pr[kk * 2 + 1] = *(const float4*)&zr0[kk * 32 + 4];
    }
    #pragma unroll
    for (int kk = 0; kk < 4; kk++) {
        pr[8 + kk * 2]     = *(const float4*)&zr1[kk * 32];
        pr[8 + kk * 2 + 1] = *(const float4*)&zr1[kk * 32 + 4];
    }

    f32x4_t acc0 = {0.f, 0.f, 0.f, 0.f};
    f32x4_t acc1 = {0.f, 0.f, 0.f, 0.f};
    #pragma unroll
    for (int kk = 0; kk < 4; kk++) {
        float4 f0 = pr[kk * 2], f1 = pr[kk * 2 + 1];
        BFU a;
        a.u[0] = f2bf(f0.x); a.u[1] = f2bf(f0.y); a.u[2] = f2bf(f0.z); a.u[3] = f2bf(f0.w);
        a.u[4] = f2bf(f1.x); a.u[5] = f2bf(f1.y); a.u[6] = f2bf(f1.z); a.u[7] = f2bf(f1.w);
        acc0 = __builtin_amdgcn_mfma_f32_16x16x32_bf16(a.v, breg[kk].v, acc0, 0, 0, 0);
    }
    #pragma unroll
    for (int kk = 0; kk < 4; kk++) {
        float4 f0 = pr[8 + kk * 2], f1 = pr[8 + kk * 2 + 1];
        BFU a;
        a.u[0] = f2bf(f0.x); a.u[1] = f2bf(f0.y); a.u[2] = f2bf(f0.z); a.u[3] = f2bf(f0.w);
        a.u[4] = f2bf(f1.x); a.u[5] = f2bf(f1.y); a.u[6] = f2bf(f1.z); a.u[7] = f2bf(f1.w);
        acc1 = __builtin_amdgcn_mfma_f32_16x16x32_bf16(a.v, breg[kk].v, acc1, 0, 0, 0);
    }

    if (l16 < HH) {
        ushort* lrow = lgts_bf + ((size_t)i * HH + l16) * NN;
        US4 o0, o1;
        #pragma unroll
        for (int r = 0; r < 4; r++) {
            int j0 = jbase + lhi * 4 + r;
            int j1 = j0 + 16;
            float lg0 = (rmi * resm[j0] == 0.f) ? MASK_NEG : acc0[r];
            float lg1 = (rmi * resm[j1] == 0.f) ? MASK_NEG : acc1[r];
            o0.us[r] = f2bf(lg0);
            o1.us[r] = f2bf(lg1);
        }
        *(uint2*)&lrow[jbase + lhi * 4]      = o0.u2;
        *(uint2*)&lrow[jbase + 16 + lhi * 4] = o1.u2;
    }
}

// ---------------- augsm: aug-GEMM (scalar+point+cb) + add pair lgts + softmax.
// grid (32 i-tiles of 16, 12 h), block 256.
__global__ __launch_bounds__(256) void augsm_kernel(const ushort* __restrict__ lgts_bf,
                                                    const ushort* __restrict__ Qaug,
                                                    const ushort* __restrict__ Kaug,
                                                    ushort* __restrict__ attn_bf)
{
    int it = blockIdx.x;        // i-tile
    int h  = blockIdx.y;
    __shared__ float Dt[16][520];   // 33.3 KB
    int tid = threadIdx.x;
    int w = tid >> 6, lane = tid & 63;
    int l16 = lane & 15, lhi = lane >> 4;

    BFU a;
    a.q = *(const uint4*)&Qaug[(((size_t)h * NN) + it * 16 + l16) * 32 + lhi * 8];

    for (int jt = w; jt < 32; jt += 4) {
        BFU b;
        b.q = *(const uint4*)&Kaug[(((size_t)h * NN) + jt * 16 + l16) * 32 + lhi * 8];
        f32x4_t acc = {0.f, 0.f, 0.f, 0.f};
        acc = __builtin_amdgcn_mfma_f32_16x16x32_bf16(a.v, b.v, acc, 0, 0, 0);
        #pragma unroll
        for (int r = 0; r < 4; r++) Dt[lhi * 4 + r][jt * 16 + l16] = acc[r];
    }
    __syncthreads();

    #pragma unroll
    for (int rr = 0; rr < 4; rr++) {
        int row = w * 4 + rr;
        const ushort* lrow = lgts_bf + (((size_t)(it * 16 + row)) * HH + h) * NN;
        float v[8]; float m = -INFINITY;
        #pragma unroll
        for (int u = 0; u < 8; u++) {
            v[u] = bf2f(lrow[lane + 64 * u]) + Dt[row][lane + 64 * u];
            m = fmaxf(m, v[u]);
        }
        for (int off = 32; off; off >>= 1) m = fmaxf(m, __shfl_xor(m, off));
        float ssum = 0.f;
        #pragma unroll
        for (int u = 0; u < 8; u++) { v[u] = __expf(v[u] - m); ssum += v[u]; }
        for (int off = 32; off; off >>= 1) ssum += __shfl_xor(ssum, off);
        float inv = 1.f / ssum;
        ushort* ag = attn_bf + (((size_t)(it * 16 + row)) * HH + h) * NN;
        #pragma unroll
        for (int u = 0; u < 8; u++) ag[lane + 64 * u] = f2bf(v[u] * inv);
    }
}

// ---------------- rpair partials: grid (4 jq, 512 i), block 256; 16-deep unroll.
__global__ __launch_bounds__(256) void rpair_kernel(const float* __restrict__ z,
                                                    const ushort* __restrict__ attn_bf,
                                                    float* __restrict__ part)
{
    int jq = blockIdx.x;
    int i  = blockIdx.y;
    __shared__ ushort pbf[128 * 12];
    __shared__ float pslab[4 * 12 * 128];
    int tid = threadIdx.x;

    if (tid < 192) {
        int h = tid >> 4, g = tid & 15;
        BFU v; v.q = *(const uint4*)&attn_bf[((size_t)i * HH + h) * NN + jq * 128 + g * 8];
        #pragma unroll
        for (int q = 0; q < 8; q++) pbf[(g * 8 + q) * 12 + h] = v.u[q];
    }
    __syncthreads();

    int w = tid >> 6, lane = tid & 63;
    int c0 = lane * 2;
    const float* zq = z + ((size_t)i * NN + jq * 128 + w * 32) * CZ + c0;
    float acc[12][2];
    #pragma unroll
    for (int h = 0; h < 12; h++) { acc[h][0] = 0.f; acc[h][1] = 0.f; }

    #pragma unroll
    for (int j0 = 0; j0 < 32; j0 += 16) {
        float2 zv[16];
        #pragma unroll
        for (int u = 0; u < 16; u++) zv[u] = *(const float2*)&zq[(size_t)(j0 + u) * CZ];
        #pragma unroll
        for (int u = 0; u < 16; u++) {
            int jl = w * 32 + j0 + u;
            const uint2* pr = (const uint2*)&pbf[jl * 12];
            uint2 pa = pr[0], pb2 = pr[1], pc = pr[2];
            float ph[12];
            ph[0]  = bf2f((ushort)(pa.x & 0xffff)); ph[1]  = bf2f((ushort)(pa.x >> 16));
            ph[2]  = bf2f((ushort)(pa.y & 0xffff)); ph[3]  = bf2f((ushort)(pa.y >> 16));
            ph[4]  = bf2f((ushort)(pb2.x & 0xffff)); ph[5]  = bf2f((ushort)(pb2.x >> 16));
            ph[6]  = bf2f((ushort)(pb2.y & 0xffff)); ph[7]  = bf2f((ushort)(pb2.y >> 16));
            ph[8]  = bf2f((ushort)(pc.x & 0xffff)); ph[9]  = bf2f((ushort)(pc.x >> 16));
            ph[10] = bf2f((ushort)(pc.y & 0xffff)); ph[11] = bf2f((ushort)(pc.y >> 16));
            #pragma unroll
            for (int h = 0; h < 12; h++) {
                acc[h][0] += ph[h] * zv[u].x;
                acc[h][1] += ph[h] * zv[u].y;
            }
        }
    }
    #pragma unroll
    for (int h = 0; h < 12; h++)
        *(float2*)&pslab[(w * 12 + h) * 128 + c0] = make_float2(acc[h][0], acc[h][1]);
    __syncthreads();

    for (int e = tid; e < 1536; e += 256) {
        float ssum = pslab[e] + pslab[1536 + e] + pslab[3072 + e] + pslab[4608 + e];
        part[((size_t)jq * NN + i) * 1536 + e] = ssum;
    }
}

// ---------------- per-head r_scalar + r_pt (+rotate back, norm) + combine rpair
__global__ void head_sum_kernel(const ushort* __restrict__ attn_bf, const float* __restrict__ tmp,
                                const float* __restrict__ rot, const float* __restrict__ tran,
                                const float* __restrict__ partR, float* __restrict__ cat)
{
    int i0 = blockIdx.x * 32;
    int h  = blockIdx.y;
    __shared__ float At[32][65];
    __shared__ float Sr[64][44];
    __shared__ float Rp[32][24];
    int tid = threadIdx.x;
    int il = tid & 31, fg = tid >> 5;
    float acc[5] = {0,0,0,0,0};

    // combine rpair quarters into cat pair channels for this (i-tile, h)
    for (int e = tid; e < 4096; e += 256) {
        int il2 = e >> 7, c = e & 127;
        size_t idx = (size_t)(i0 + il2) * 1536 + h * 128 + c;
        float ssum = partR[idx]
                   + partR[(size_t)NN * 1536 + idx]
                   + partR[(size_t)2 * NN * 1536 + idx]
                   + partR[(size_t)3 * NN * 1536 + idx];
        cat[(size_t)(i0 + il2) * CATDIM + h * CATH + 48 + c] = ssum;
    }

    for (int jc = 0; jc < NN; jc += 64) {
        {
            int r = tid >> 3, c8 = (tid & 7) * 8;
            const ushort* src = attn_bf + ((size_t)(i0 + r) * HH + h) * NN + jc + c8;
            BFU v; v.q = *(const uint4*)src;
            #pragma unroll
            for (int q = 0; q < 8; q++) At[r][c8 + q] = bf2f(v.u[q]);
        }
        {
            int jr = tid >> 2, d4 = (tid & 3) * 4;
            *(float4*)&Sr[jr][d4] = *(const float4*)&tmp[(size_t)(jc + jr) * TMPW + 384 + h * 16 + d4];
        }
        for (int e = tid; e < 384; e += 256) {
            int jr = e / 6, p4 = (e % 6) * 4;
            *(float4*)&Sr[jr][16 + p4] = *(const float4*)&tmp[(size_t)(jc + jr) * TMPW + 864 + h * 24 + p4];
        }
        __syncthreads();
        #pragma unroll 4
        for (int j = 0; j < 64; j++) {
            float a = At[il][j];
            #pragma unroll
            for (int q = 0; q < 5; q++) acc[q] += a * Sr[j][fg * 5 + q];
        }
        __syncthreads();
    }

    float* cbase = cat + (size_t)(i0 + il) * CATDIM + h * CATH;
    #pragma unroll
    for (int q = 0; q < 5; q++) {
        int f = fg * 5 + q;
        if (f < 16) cbase[f] = acc[q];
        else Rp[il][f - 16] = acc[q];
    }
    __syncthreads();

    {
        int il2 = tid >> 3, p = tid & 7;
        int i = i0 + il2;
        float gx = Rp[il2][p * 3 + 0] - tran[i * 3 + 0];
        float gy = Rp[il2][p * 3 + 1] - tran[i * 3 + 1];
        float gz = Rp[il2][p * 3 + 2] - tran[i * 3 + 2];
        const float* R = rot + i * 9;
        float lx = R[0] * gx + R[3] * gy + R[6] * gz;
        float ly = R[1] * gx + R[4] * gy + R[7] * gz;
        float lz = R[2] * gx + R[5] * gy + R[8] * gz;
        float nrm = sqrtf(lx * lx + ly * ly + lz * lz + 1e-8f);
        float* cp = cat + (size_t)i * CATDIM + h * CATH;
        cp[16 + p * 3 + 0] = lx; cp[16 + p * 3 + 1] = ly; cp[16 + p * 3 + 2] = lz;
        cp[40 + p] = nrm;
    }
}

// ---------------- out GEMM, K-split
__global__ void out_gemm_split_kernel(const float* __restrict__ cat, const float* __restrict__ Wout,
                                      float* __restrict__ part)
{
    int n0 = blockIdx.x * 64;
    int i0 = blockIdx.y * 64;
    int ks = blockIdx.z * KSPL;
    __shared__ float St[32][68];
    __shared__ float Bs[32][68];
    int tid = threadIdx.x;
    int ty = tid >> 4, tx = tid & 15;
    float acc[4][4] = {{0,0,0,0},{0,0,0,0},{0,0,0,0},{0,0,0,0}};

    for (int k0 = 0; k0 < KSPL; k0 += 32) {
        {
            int r = tid >> 2, c8 = (tid & 3) * 8;
            const float* src = cat + (size_t)(i0 + r) * CATDIM + ks + k0 + c8;
            float4 v0 = *(const float4*)src;
            float4 v1 = *(const float4*)(src + 4);
            St[c8+0][r]=v0.x; St[c8+1][r]=v0.y; St[c8+2][r]=v0.z; St[c8+3][r]=v0.w;
            St[c8+4][r]=v1.x; St[c8+5][r]=v1.y; St[c8+6][r]=v1.z; St[c8+7][r]=v1.w;
        }
        {
            int r = tid >> 3, c8 = (tid & 7) * 8;
            const float* src = Wout + (size_t)(ks + k0 + r) * CSD + n0 + c8;
            *(float4*)&Bs[r][c8]     = *(const float4*)src;
            *(float4*)&Bs[r][c8 + 4] = *(const float4*)(src + 4);
        }
        __syncthreads();
        #pragma unroll
        for (int k = 0; k < 32; k++) {
            float4 a = *(const float4*)&St[k][ty * 4];
            float4 b = *(const float4*)&Bs[k][tx * 4];
            float av[4] = {a.x, a.y, a.z, a.w};
            float bv[4] = {b.x, b.y, b.z, b.w};
            #pragma unroll
            for (int r = 0; r < 4; r++)
                #pragma unroll
                for (int c = 0; c < 4; c++) acc[r][c] += av[r] * bv[c];
        }
        __syncthreads();
    }
    #pragma unroll
    for (int r = 0; r < 4; r++) {
        float4 v = make_float4(acc[r][0], acc[r][1], acc[r][2], acc[r][3]);
        *(float4*)&part[((size_t)blockIdx.z * NN + i0 + ty * 4 + r) * CSD + n0 + tx * 4] = v;
    }
}

__global__ void reduce_out_kernel(const float* __restrict__ part, const float* __restrict__ bout,
                                  float* __restrict__ out)
{
    int v = blockIdx.x * 256 + threadIdx.x;
    int n4 = v % 96;
    float4 o = ((const float4*)bout)[n4];
    const float4* p4 = (const float4*)part;
    #pragma unroll
    for (int s = 0; s < NSPLIT; s++) {
        float4 t = p4[(size_t)s * 49152 + v];
        o.x += t.x; o.y += t.y; o.z += t.z; o.w += t.w;
    }
    ((float4*)out)[v] = o;
}

extern "C" void kernel_launch(void* const* d_in, const int* in_sizes, int n_in,
                              void* d_out, int out_size, void* d_ws, size_t ws_size,
                              hipStream_t stream) {
    const float* s    = (const float*)d_in[0];
    const float* z    = (const float*)d_in[1];
    const float* rot  = (const float*)d_in[2];
    const float* tran = (const float*)d_in[3];
    const float* resm = (const float*)d_in[4];
    const float* Wsq  = (const float*)d_in[5];  const float* bsq = (const float*)d_in[6];
    const float* Wsk  = (const float*)d_in[7];  const float* bsk = (const float*)d_in[8];
    const float* Wsv  = (const float*)d_in[9];  const float* bsv = (const float*)d_in[10];
    const float* Wsb  = (const float*)d_in[11]; const float* bsb = (const float*)d_in[12];
    const float* Wpq  = (const float*)d_in[13]; const float* bpq = (const float*)d_in[14];
    const float* Wpk  = (const float*)d_in[15]; const float* bpk = (const float*)d_in[16];
    const float* Wpv  = (const float*)d_in[17]; const float* bpv = (const float*)d_in[18];
    const float* watt = (const float*)d_in[19]; const float* batt = (const float*)d_in[20];
    const float* tpw  = (const float*)d_in[21];
    const float* Wout = (const float*)d_in[22]; const float* bout = (const float*)d_in[23];
    float* out = (float*)d_out;
    float* ws  = (float*)d_ws;

    float*  tmp     = ws;                        // 589824
    ushort* attn_bf = (ushort*)(ws + 589824);    // 1572864 f-slots
    ushort* lgts_bf = (ushort*)(ws + 2162688);   // 1572864 f-slots
    float*  partR   = ws + 3735552;              // 3145728
    ushort* Qaug    = (ushort*)(ws + 6881280);   // 98304 f-slots
    ushort* Kaug    = (ushort*)(ws + 6979584);   // 98304 f-slots
    float*  cat     = ws + 7077888;              // 1081344
    float*  partO   = ws + 8159232;              // 1179648

    proj_gemm_kernel<<<dim3(24, 16), 256, 0, stream>>>(s, rot, tran,
                                                       Wsq, bsq, Wsk, bsk, Wsv, bsv,
                                                       Wpq, bpq, Wpk, bpk, Wpv, bpv, tmp);
    augprep_kernel<<<512, 256, 0, stream>>>(tmp, watt, batt, tpw, bsb, Qaug, Kaug);
    zlogits_kernel<<<dim3(4, 512), 256, 0, stream>>>(z, resm, Wsb, watt, lgts_bf);
    augsm_kernel<<<dim3(32, 12), 256, 0, stream>>>(lgts_bf, Qaug, Kaug, attn_bf);
    rpair_kernel<<<dim3(4, 512), 256, 0, stream>>>(z, attn_bf, partR);
    head_sum_kernel<<<dim3(16, 12), 256, 0, stream>>>(attn_bf, tmp, rot, tran, partR, cat);
    out_gemm_split_kernel<<<dim3(6, 8, NSPLIT), 256, 0, stream>>>(cat, Wout, partO);
    reduce_out_kernel<<<192, 256, 0, stream>>>(partO, bout, out);
}

// Round 15
// 180.483 us; speedup vs baseline: 1.4797x; 1.0133x over previous
//
#include <hip/hip_runtime.h>
#include <hip/hip_bf16.h>
#include <math.h>

#define NN 512
#define CSD 384
#define CZ 128
#define HH 12
#define TMPW 1152          // 192 sq | 192 sk | 192 sv | 144 pq | 144 pk | 288 pv
#define CATH 176
#define CATDIM 2112
#define NSPLIT 6
#define KSPL 352

#define SW 0.14433756729740643f
#define PW 0.13608276348795434f
#define ZW 0.57735026918962576f
#define NEG_INF -3.4028234663852886e38f
#define MASK_NEG -1.0e30f

typedef float f32x4_t __attribute__((ext_vector_type(4)));
typedef short bf16x8_t __attribute__((ext_vector_type(8)));

union BFU { uint4 q; bf16x8_t v; ushort u[8]; };
union US4 { ushort us[4]; uint2 u2; };

static __device__ __forceinline__ ushort f2bf(float f) {
    __hip_bfloat16 h = __float2bfloat16(f);
    return *reinterpret_cast<ushort*>(&h);
}
static __device__ __forceinline__ float bf2f(ushort u) {
    unsigned int v = ((unsigned int)u) << 16;
    return __uint_as_float(v);
}

// ---------------- proj GEMM + fused rotation: tmp[512][1152] = s @ Wcat + bias
__global__ void proj_gemm_kernel(const float* __restrict__ s, const float* __restrict__ rot,
                                 const float* __restrict__ tran,
                                 const float* __restrict__ Wsq, const float* __restrict__ bsq,
                                 const float* __restrict__ Wsk, const float* __restrict__ bsk,
                                 const float* __restrict__ Wsv, const float* __restrict__ bsv,
                                 const float* __restrict__ Wpq, const float* __restrict__ bpq,
                                 const float* __restrict__ Wpk, const float* __restrict__ bpk,
                                 const float* __restrict__ Wpv, const float* __restrict__ bpv,
                                 float* __restrict__ tmp)
{
    int bx = blockIdx.x;            // 24 f-tiles of 48
    int n0 = blockIdx.y * 32;       // 16 n-tiles
    int f0 = bx * 48;
    const float* W; const float* bb; int dout; int segstart;
    if (bx < 4)       { W = Wsq; bb = bsq; dout = 192; segstart = 0; }
    else if (bx < 8)  { W = Wsk; bb = bsk; dout = 192; segstart = 192; }
    else if (bx < 12) { W = Wsv; bb = bsv; dout = 192; segstart = 384; }
    else if (bx < 15) { W = Wpq; bb = bpq; dout = 144; segstart = 576; }
    else if (bx < 18) { W = Wpk; bb = bpk; dout = 144; segstart = 720; }
    else              { W = Wpv; bb = bpv; dout = 288; segstart = 864; }
    int colbase = f0 - segstart;

    __shared__ float St[32][34];
    __shared__ float Ws[32][49];
    int tid = threadIdx.x;
    int ty = tid >> 4, tx = tid & 15;
    float acc[2][3] = {{0,0,0},{0,0,0}};

    for (int k0 = 0; k0 < CSD; k0 += 32) {
        {
            int r = tid >> 3, c4 = (tid & 7) * 4;
            float4 v = *(const float4*)&s[(size_t)(n0 + r) * CSD + k0 + c4];
            St[c4 + 0][r] = v.x; St[c4 + 1][r] = v.y; St[c4 + 2][r] = v.z; St[c4 + 3][r] = v.w;
        }
        for (int e = tid; e < 1536; e += 256) {
            int r = e / 48, c = e % 48;
            Ws[r][c] = W[(size_t)(k0 + r) * dout + colbase + c];
        }
        __syncthreads();
        #pragma unroll
        for (int k = 0; k < 32; k++) {
            float2 a = *(const float2*)&St[k][ty * 2];
            float b0 = Ws[k][tx * 3], b1 = Ws[k][tx * 3 + 1], b2 = Ws[k][tx * 3 + 2];
            acc[0][0] += a.x * b0; acc[0][1] += a.x * b1; acc[0][2] += a.x * b2;
            acc[1][0] += a.y * b0; acc[1][1] += a.y * b1; acc[1][2] += a.y * b2;
        }
        __syncthreads();
    }
    float bv0 = bb[colbase + tx * 3], bv1 = bb[colbase + tx * 3 + 1], bv2 = bb[colbase + tx * 3 + 2];
    #pragma unroll
    for (int r = 0; r < 2; r++) {
        int n = n0 + ty * 2 + r;
        float v0 = acc[r][0] + bv0, v1 = acc[r][1] + bv1, v2 = acc[r][2] + bv2;
        float* o = tmp + (size_t)n * TMPW + f0 + tx * 3;
        if (bx >= 12) {
            const float* R = rot + n * 9;
            const float* T = tran + n * 3;
            float g0 = R[0] * v0 + R[1] * v1 + R[2] * v2 + T[0];
            float g1 = R[3] * v0 + R[4] * v1 + R[5] * v2 + T[1];
            float g2 = R[6] * v0 + R[7] * v1 + R[8] * v2 + T[2];
            o[0] = g0; o[1] = g1; o[2] = g2;
        } else {
            o[0] = v0; o[1] = v1; o[2] = v2;
        }
    }
}

// ---------------- augprep: build Qaug/Kaug [h][n][32] bf16 from tmp.
__global__ void augprep_kernel(const float* __restrict__ tmp,
                               const float* __restrict__ watt, const float* __restrict__ batt,
                               const float* __restrict__ tpw, const float* __restrict__ bsb,
                               ushort* __restrict__ Qaug, ushort* __restrict__ Kaug)
{
    int n = blockIdx.x;
    int tid = threadIdx.x;
    float w0 = watt[0], w1 = watt[1], w2 = watt[2], ba = batt[0];
    float A2 = w2 * ZW;
    __shared__ float nq[12], nk[12];
    if (tid < 24) {
        int h = tid >> 1, which = tid & 1;
        const float* p = tmp + (size_t)n * TMPW + (which ? 720 : 576) + h * 12;
        float s2 = 0.f;
        #pragma unroll
        for (int d = 0; d < 12; d++) s2 += p[d] * p[d];
        if (which) nk[h] = s2; else nq[h] = s2;
    }
    __syncthreads();

    for (int f = tid; f < 384; f += 256) {
        if (f < 192) {
            int h = f >> 4, k = f & 15;
            float sq = tmp[(size_t)n * TMPW + h * 16 + k] * (SW * w0);
            float sk = tmp[(size_t)n * TMPW + 192 + h * 16 + k];
            Qaug[((size_t)h * NN + n) * 32 + k] = f2bf(sq);
            Kaug[((size_t)h * NN + n) * 32 + k] = f2bf(sk);
        } else if (f < 336) {
            int e = f - 192; int h = e / 12, d = e % 12;
            float cpt = -0.5f * log1pf(expf(tpw[h])) * PW * w1;
            float pq = tmp[(size_t)n * TMPW + 576 + h * 12 + d];
            float pk = tmp[(size_t)n * TMPW + 720 + h * 12 + d];
            Qaug[((size_t)h * NN + n) * 32 + 16 + d] = f2bf(-2.f * cpt * pq);
            Kaug[((size_t)h * NN + n) * 32 + 16 + d] = f2bf(pk);
        } else {
            int e = f - 336; int h = e >> 2, sl = e & 3;
            float cpt = -0.5f * log1pf(expf(tpw[h])) * PW * w1;
            float qv, kv;
            if (sl == 0)      { qv = cpt * nq[h];      kv = 1.f; }
            else if (sl == 1) { qv = cpt;              kv = nk[h]; }
            else if (sl == 2) { qv = A2 * bsb[h] + ba; kv = 1.f; }
            else              { qv = 0.f;              kv = 0.f; }
            Qaug[((size_t)h * NN + n) * 32 + 28 + sl] = f2bf(qv);
            Kaug[((size_t)h * NN + n) * 32 + 28 + sl] = f2bf(kv);
        }
    }
}

// ---------------- zlogits: pure z-stream pair-bias via register MFMA.
// Also persists the converted bf16 z as z_bf[i][j][c] (dense 16B stores) so
// the second z pass (rpair) reads half the bytes.
__global__ __launch_bounds__(256) void zlogits_kernel(const float* __restrict__ z,
                                                      const float* __restrict__ resm,
                                                      const float* __restrict__ Wsb,
                                                      const float* __restrict__ watt,
                                                      ushort* __restrict__ lgts_bf,
                                                      ushort* __restrict__ z_bf)
{
    int jc = blockIdx.x;
    int i  = blockIdx.y;
    int tid = threadIdx.x;
    int w = tid >> 6, lane = tid & 63;
    int l16 = lane & 15, lhi = lane >> 4;
    float A2 = watt[2] * ZW;

    BFU breg[4];
    #pragma unroll
    for (int kk = 0; kk < 4; kk++) {
        #pragma unroll
        for (int e = 0; e < 8; e++) {
            int k = kk * 32 + lhi * 8 + e;
            float v = (l16 < HH) ? Wsb[k * HH + l16] * A2 : 0.f;
            breg[kk].u[e] = f2bf(v);
        }
    }

    const float* zi = z + (size_t)i * NN * CZ;
    float rmi = resm[i];
    int jbase = jc * 128 + w * 32;      // wave owns rows jbase..jbase+31

    const float* zr0 = zi + (size_t)(jbase + l16) * CZ + lhi * 8;
    const float* zr1 = zi + (size_t)(jbase + 16 + l16) * CZ + lhi * 8;
    float4 pr[16];
    #pragma unroll
    for (int kk = 0; kk < 4; kk++) {
        pr[kk * 2]     = *(const float4*)&zr0[kk * 32];
        pr[kk * 2 + 1] = *(const float4*)&zr0[kk * 32 + 4];
    }
    #pragma unroll
    for (int kk = 0; kk < 4; kk++) {
        pr[8 + kk * 2]     = *(const float4*)&zr1[kk * 32];
        pr[8 + kk * 2 + 1] = *(const float4*)&zr1[kk * 32 + 4];
    }

    ushort* zb0 = z_bf + ((size_t)i * NN + jbase + l16) * CZ + lhi * 8;
    ushort* zb1 = z_bf + ((size_t)i * NN + jbase + 16 + l16) * CZ + lhi * 8;

    f32x4_t acc0 = {0.f, 0.f, 0.f, 0.f};
    f32x4_t acc1 = {0.f, 0.f, 0.f, 0.f};
    #pragma unroll
    for (int kk = 0; kk < 4; kk++) {
        float4 f0 = pr[kk * 2], f1 = pr[kk * 2 + 1];
        BFU a;
        a.u[0] = f2bf(f0.x); a.u[1] = f2bf(f0.y); a.u[2] = f2bf(f0.z); a.u[3] = f2bf(f0.w);
        a.u[4] = f2bf(f1.x); a.u[5] = f2bf(f1.y); a.u[6] = f2bf(f1.z); a.u[7] = f2bf(f1.w);
        acc0 = __builtin_amdgcn_mfma_f32_16x16x32_bf16(a.v, breg[kk].v, acc0, 0, 0, 0);
        *(uint4*)&zb0[kk * 32] = a.q;
    }
    #pragma unroll
    for (int kk = 0; kk < 4; kk++) {
        float4 f0 = pr[8 + kk * 2], f1 = pr[8 + kk * 2 + 1];
        BFU a;
        a.u[0] = f2bf(f0.x); a.u[1] = f2bf(f0.y); a.u[2] = f2bf(f0.z); a.u[3] = f2bf(f0.w);
        a.u[4] = f2bf(f1.x); a.u[5] = f2bf(f1.y); a.u[6] = f2bf(f1.z); a.u[7] = f2bf(f1.w);
        acc1 = __builtin_amdgcn_mfma_f32_16x16x32_bf16(a.v, breg[kk].v, acc1, 0, 0, 0);
        *(uint4*)&zb1[kk * 32] = a.q;
    }

    if (l16 < HH) {
        ushort* lrow = lgts_bf + ((size_t)i * HH + l16) * NN;
        US4 o0, o1;
        #pragma unroll
        for (int r = 0; r < 4; r++) {
            int j0 = jbase + lhi * 4 + r;
            int j1 = j0 + 16;
            float lg0 = (rmi * resm[j0] == 0.f) ? MASK_NEG : acc0[r];
            float lg1 = (rmi * resm[j1] == 0.f) ? MASK_NEG : acc1[r];
            o0.us[r] = f2bf(lg0);
            o1.us[r] = f2bf(lg1);
        }
        *(uint2*)&lrow[jbase + lhi * 4]      = o0.u2;
        *(uint2*)&lrow[jbase + 16 + lhi * 4] = o1.u2;
    }
}

// ---------------- augsm: aug-GEMM (scalar+point+cb) + add pair lgts + softmax.
__global__ __launch_bounds__(256) void augsm_kernel(const ushort* __restrict__ lgts_bf,
                                                    const ushort* __restrict__ Qaug,
                                                    const ushort* __restrict__ Kaug,
                                                    ushort* __restrict__ attn_bf)
{
    int it = blockIdx.x;        // i-tile
    int h  = blockIdx.y;
    __shared__ float Dt[16][520];   // 33.3 KB
    int tid = threadIdx.x;
    int w = tid >> 6, lane = tid & 63;
    int l16 = lane & 15, lhi = lane >> 4;

    BFU a;
    a.q = *(const uint4*)&Qaug[(((size_t)h * NN) + it * 16 + l16) * 32 + lhi * 8];

    for (int jt = w; jt < 32; jt += 4) {
        BFU b;
        b.q = *(const uint4*)&Kaug[(((size_t)h * NN) + jt * 16 + l16) * 32 + lhi * 8];
        f32x4_t acc = {0.f, 0.f, 0.f, 0.f};
        acc = __builtin_amdgcn_mfma_f32_16x16x32_bf16(a.v, b.v, acc, 0, 0, 0);
        #pragma unroll
        for (int r = 0; r < 4; r++) Dt[lhi * 4 + r][jt * 16 + l16] = acc[r];
    }
    __syncthreads();

    #pragma unroll
    for (int rr = 0; rr < 4; rr++) {
        int row = w * 4 + rr;
        const ushort* lrow = lgts_bf + (((size_t)(it * 16 + row)) * HH + h) * NN;
        float v[8]; float m = -INFINITY;
        #pragma unroll
        for (int u = 0; u < 8; u++) {
            v[u] = bf2f(lrow[lane + 64 * u]) + Dt[row][lane + 64 * u];
            m = fmaxf(m, v[u]);
        }
        for (int off = 32; off; off >>= 1) m = fmaxf(m, __shfl_xor(m, off));
        float ssum = 0.f;
        #pragma unroll
        for (int u = 0; u < 8; u++) { v[u] = __expf(v[u] - m); ssum += v[u]; }
        for (int off = 32; off; off >>= 1) ssum += __shfl_xor(ssum, off);
        float inv = 1.f / ssum;
        ushort* ag = attn_bf + (((size_t)(it * 16 + row)) * HH + h) * NN;
        #pragma unroll
        for (int u = 0; u < 8; u++) ag[lane + 64 * u] = f2bf(v[u] * inv);
    }
}

// ---------------- rpair partials: grid (4 jq, 512 i); reads bf16 z_bf (half bytes).
__global__ __launch_bounds__(256) void rpair_kernel(const ushort* __restrict__ z_bf,
                                                    const ushort* __restrict__ attn_bf,
                                                    float* __restrict__ part)
{
    int jq = blockIdx.x;
    int i  = blockIdx.y;
    __shared__ ushort pbf[128 * 12];
    __shared__ float pslab[4 * 12 * 128];
    int tid = threadIdx.x;

    if (tid < 192) {
        int h = tid >> 4, g = tid & 15;
        BFU v; v.q = *(const uint4*)&attn_bf[((size_t)i * HH + h) * NN + jq * 128 + g * 8];
        #pragma unroll
        for (int q = 0; q < 8; q++) pbf[(g * 8 + q) * 12 + h] = v.u[q];
    }
    __syncthreads();

    int w = tid >> 6, lane = tid & 63;
    int c0 = lane * 2;
    const ushort* zq = z_bf + ((size_t)i * NN + jq * 128 + w * 32) * CZ + c0;
    float acc[12][2];
    #pragma unroll
    for (int h = 0; h < 12; h++) { acc[h][0] = 0.f; acc[h][1] = 0.f; }

    #pragma unroll
    for (int j0 = 0; j0 < 32; j0 += 16) {
        uint zv[16];
        #pragma unroll
        for (int u = 0; u < 16; u++) zv[u] = *(const uint*)&zq[(size_t)(j0 + u) * CZ];
        #pragma unroll
        for (int u = 0; u < 16; u++) {
            float zx = bf2f((ushort)(zv[u] & 0xffff));
            float zy = bf2f((ushort)(zv[u] >> 16));
            int jl = w * 32 + j0 + u;
            const uint2* pr = (const uint2*)&pbf[jl * 12];
            uint2 pa = pr[0], pb2 = pr[1], pc = pr[2];
            float ph[12];
            ph[0]  = bf2f((ushort)(pa.x & 0xffff)); ph[1]  = bf2f((ushort)(pa.x >> 16));
            ph[2]  = bf2f((ushort)(pa.y & 0xffff)); ph[3]  = bf2f((ushort)(pa.y >> 16));
            ph[4]  = bf2f((ushort)(pb2.x & 0xffff)); ph[5]  = bf2f((ushort)(pb2.x >> 16));
            ph[6]  = bf2f((ushort)(pb2.y & 0xffff)); ph[7]  = bf2f((ushort)(pb2.y >> 16));
            ph[8]  = bf2f((ushort)(pc.x & 0xffff)); ph[9]  = bf2f((ushort)(pc.x >> 16));
            ph[10] = bf2f((ushort)(pc.y & 0xffff)); ph[11] = bf2f((ushort)(pc.y >> 16));
            #pragma unroll
            for (int h = 0; h < 12; h++) {
                acc[h][0] += ph[h] * zx;
                acc[h][1] += ph[h] * zy;
            }
        }
    }
    #pragma unroll
    for (int h = 0; h < 12; h++)
        *(float2*)&pslab[(w * 12 + h) * 128 + c0] = make_float2(acc[h][0], acc[h][1]);
    __syncthreads();

    for (int e = tid; e < 1536; e += 256) {
        float ssum = pslab[e] + pslab[1536 + e] + pslab[3072 + e] + pslab[4608 + e];
        part[((size_t)jq * NN + i) * 1536 + e] = ssum;
    }
}

// ---------------- per-head r_scalar + r_pt (+rotate back, norm) + combine rpair
__global__ void head_sum_kernel(const ushort* __restrict__ attn_bf, const float* __restrict__ tmp,
                                const float* __restrict__ rot, const float* __restrict__ tran,
                                const float* __restrict__ partR, float* __restrict__ cat)
{
    int i0 = blockIdx.x * 32;
    int h  = blockIdx.y;
    __shared__ float At[32][65];
    __shared__ float Sr[64][44];
    __shared__ float Rp[32][24];
    int tid = threadIdx.x;
    int il = tid & 31, fg = tid >> 5;
    float acc[5] = {0,0,0,0,0};

    for (int e = tid; e < 4096; e += 256) {
        int il2 = e >> 7, c = e & 127;
        size_t idx = (size_t)(i0 + il2) * 1536 + h * 128 + c;
        float ssum = partR[idx]
                   + partR[(size_t)NN * 1536 + idx]
                   + partR[(size_t)2 * NN * 1536 + idx]
                   + partR[(size_t)3 * NN * 1536 + idx];
        cat[(size_t)(i0 + il2) * CATDIM + h * CATH + 48 + c] = ssum;
    }

    for (int jc = 0; jc < NN; jc += 64) {
        {
            int r = tid >> 3, c8 = (tid & 7) * 8;
            const ushort* src = attn_bf + ((size_t)(i0 + r) * HH + h) * NN + jc + c8;
            BFU v; v.q = *(const uint4*)src;
            #pragma unroll
            for (int q = 0; q < 8; q++) At[r][c8 + q] = bf2f(v.u[q]);
        }
        {
            int jr = tid >> 2, d4 = (tid & 3) * 4;
            *(float4*)&Sr[jr][d4] = *(const float4*)&tmp[(size_t)(jc + jr) * TMPW + 384 + h * 16 + d4];
        }
        for (int e = tid; e < 384; e += 256) {
            int jr = e / 6, p4 = (e % 6) * 4;
            *(float4*)&Sr[jr][16 + p4] = *(const float4*)&tmp[(size_t)(jc + jr) * TMPW + 864 + h * 24 + p4];
        }
        __syncthreads();
        #pragma unroll 4
        for (int j = 0; j < 64; j++) {
            float a = At[il][j];
            #pragma unroll
            for (int q = 0; q < 5; q++) acc[q] += a * Sr[j][fg * 5 + q];
        }
        __syncthreads();
    }

    float* cbase = cat + (size_t)(i0 + il) * CATDIM + h * CATH;
    #pragma unroll
    for (int q = 0; q < 5; q++) {
        int f = fg * 5 + q;
        if (f < 16) cbase[f] = acc[q];
        else Rp[il][f - 16] = acc[q];
    }
    __syncthreads();

    {
        int il2 = tid >> 3, p = tid & 7;
        int i = i0 + il2;
        float gx = Rp[il2][p * 3 + 0] - tran[i * 3 + 0];
        float gy = Rp[il2][p * 3 + 1] - tran[i * 3 + 1];
        float gz = Rp[il2][p * 3 + 2] - tran[i * 3 + 2];
        const float* R = rot + i * 9;
        float lx = R[0] * gx + R[3] * gy + R[6] * gz;
        float ly = R[1] * gx + R[4] * gy + R[7] * gz;
        float lz = R[2] * gx + R[5] * gy + R[8] * gz;
        float nrm = sqrtf(lx * lx + ly * ly + lz * lz + 1e-8f);
        float* cp = cat + (size_t)i * CATDIM + h * CATH;
        cp[16 + p * 3 + 0] = lx; cp[16 + p * 3 + 1] = ly; cp[16 + p * 3 + 2] = lz;
        cp[40 + p] = nrm;
    }
}

// ---------------- out GEMM, K-split
__global__ void out_gemm_split_kernel(const float* __restrict__ cat, const float* __restrict__ Wout,
                                      float* __restrict__ part)
{
    int n0 = blockIdx.x * 64;
    int i0 = blockIdx.y * 64;
    int ks = blockIdx.z * KSPL;
    __shared__ float St[32][68];
    __shared__ float Bs[32][68];
    int tid = threadIdx.x;
    int ty = tid >> 4, tx = tid & 15;
    float acc[4][4] = {{0,0,0,0},{0,0,0,0},{0,0,0,0},{0,0,0,0}};

    for (int k0 = 0; k0 < KSPL; k0 += 32) {
        {
            int r = tid >> 2, c8 = (tid & 3) * 8;
            const float* src = cat + (size_t)(i0 + r) * CATDIM + ks + k0 + c8;
            float4 v0 = *(const float4*)src;
            float4 v1 = *(const float4*)(src + 4);
            St[c8+0][r]=v0.x; St[c8+1][r]=v0.y; St[c8+2][r]=v0.z; St[c8+3][r]=v0.w;
            St[c8+4][r]=v1.x; St[c8+5][r]=v1.y; St[c8+6][r]=v1.z; St[c8+7][r]=v1.w;
        }
        {
            int r = tid >> 3, c8 = (tid & 7) * 8;
            const float* src = Wout + (size_t)(ks + k0 + r) * CSD + n0 + c8;
            *(float4*)&Bs[r][c8]     = *(const float4*)src;
            *(float4*)&Bs[r][c8 + 4] = *(const float4*)(src + 4);
        }
        __syncthreads();
        #pragma unroll
        for (int k = 0; k < 32; k++) {
            float4 a = *(const float4*)&St[k][ty * 4];
            float4 b = *(const float4*)&Bs[k][tx * 4];
            float av[4] = {a.x, a.y, a.z, a.w};
            float bv[4] = {b.x, b.y, b.z, b.w};
            #pragma unroll
            for (int r = 0; r < 4; r++)
                #pragma unroll
                for (int c = 0; c < 4; c++) acc[r][c] += av[r] * bv[c];
        }
        __syncthreads();
    }
    #pragma unroll
    for (int r = 0; r < 4; r++) {
        float4 v = make_float4(acc[r][0], acc[r][1], acc[r][2], acc[r][3]);
        *(float4*)&part[((size_t)blockIdx.z * NN + i0 + ty * 4 + r) * CSD + n0 + tx * 4] = v;
    }
}

__global__ void reduce_out_kernel(const float* __restrict__ part, const float* __restrict__ bout,
                                  float* __restrict__ out)
{
    int v = blockIdx.x * 256 + threadIdx.x;
    int n4 = v % 96;
    float4 o = ((const float4*)bout)[n4];
    const float4* p4 = (const float4*)part;
    #pragma unroll
    for (int s = 0; s < NSPLIT; s++) {
        float4 t = p4[(size_t)s * 49152 + v];
        o.x += t.x; o.y += t.y; o.z += t.z; o.w += t.w;
    }
    ((float4*)out)[v] = o;
}

extern "C" void kernel_launch(void* const* d_in, const int* in_sizes, int n_in,
                              void* d_out, int out_size, void* d_ws, size_t ws_size,
                              hipStream_t stream) {
    const float* s    = (const float*)d_in[0];
    const float* z    = (const float*)d_in[1];
    const float* rot  = (const float*)d_in[2];
    const float* tran = (const float*)d_in[3];
    const float* resm = (const float*)d_in[4];
    const float* Wsq  = (const float*)d_in[5];  const float* bsq = (const float*)d_in[6];
    const float* Wsk  = (const float*)d_in[7];  const float* bsk = (const float*)d_in[8];
    const float* Wsv  = (const float*)d_in[9];  const float* bsv = (const float*)d_in[10];
    const float* Wsb  = (const float*)d_in[11]; const float* bsb = (const float*)d_in[12];
    const float* Wpq  = (const float*)d_in[13]; const float* bpq = (const float*)d_in[14];
    const float* Wpk  = (const float*)d_in[15]; const float* bpk = (const float*)d_in[16];
    const float* Wpv  = (const float*)d_in[17]; const float* bpv = (const float*)d_in[18];
    const float* watt = (const float*)d_in[19]; const float* batt = (const float*)d_in[20];
    const float* tpw  = (const float*)d_in[21];
    const float* Wout = (const float*)d_in[22]; const float* bout = (const float*)d_in[23];
    float* out = (float*)d_out;
    float* ws  = (float*)d_ws;

    float*  tmp     = ws;                        // 589824
    ushort* attn_bf = (ushort*)(ws + 589824);    // 1572864 f-slots
    ushort* lgts_bf = (ushort*)(ws + 2162688);   // 1572864 f-slots
    float*  partR   = ws + 3735552;              // 3145728
    ushort* Qaug    = (ushort*)(ws + 6881280);   // 98304 f-slots
    ushort* Kaug    = (ushort*)(ws + 6979584);   // 98304 f-slots
    float*  cat     = ws + 7077888;              // 1081344
    ushort* z_bf    = (ushort*)(ws + 8159232);   // 16777216 f-slots
    // partO aliases lgts_bf+partR region (both dead after head_sum runs)
    float*  partO   = ws + 2162688;              // 1179648 (fits in lgts_bf's 1572864)

    proj_gemm_kernel<<<dim3(24, 16), 256, 0, stream>>>(s, rot, tran,
                                                       Wsq, bsq, Wsk, bsk, Wsv, bsv,
                                                       Wpq, bpq, Wpk, bpk, Wpv, bpv, tmp);
    augprep_kernel<<<512, 256, 0, stream>>>(tmp, watt, batt, tpw, bsb, Qaug, Kaug);
    zlogits_kernel<<<dim3(4, 512), 256, 0, stream>>>(z, resm, Wsb, watt, lgts_bf, z_bf);
    augsm_kernel<<<dim3(32, 12), 256, 0, stream>>>(lgts_bf, Qaug, Kaug, attn_bf);
    rpair_kernel<<<dim3(4, 512), 256, 0, stream>>>(z_bf, attn_bf, partR);
    head_sum_kernel<<<dim3(16, 12), 256, 0, stream>>>(attn_bf, tmp, rot, tran, partR, cat);
    out_gemm_split_kernel<<<dim3(6, 8, NSPLIT), 256, 0, stream>>>(cat, Wout, partO);
    reduce_out_kernel<<<192, 256, 0, stream>>>(partO, bout, out);
}